// Round 15
// baseline (522.227 us; speedup 1.0000x reference)
//
#include <hip/hip_runtime.h>
#include <hip/hip_bf16.h>
#include <math.h>

#define NB   64      // batch
#define D2   64      // objects per batch
#define OBJ  26      // K+2 features per object
#define NQST 11
#define HID  256
#define NOUT 28
#define NTILE 32     // p-tiles per batch (2 p's each, pp loop)
#define HSTR 528     // h row stride in BYTES: 512 data + 16 pad -> 4-bank shift
                     // per row (2-way aliasing = free) AND ks-affine addresses
#define HBUF (D2 * HSTR)   // 33792 B per h buffer

typedef __attribute__((ext_vector_type(8))) short s16x8;
typedef __attribute__((ext_vector_type(4))) float f32x4;
typedef __attribute__((ext_vector_type(2))) unsigned int u32x2;

__device__ __forceinline__ unsigned short f2bf(float f) {
    __hip_bfloat16 h = __float2bfloat16(f);
    union { __hip_bfloat16 h; unsigned short u; } v; v.h = h; return v.u;
}
__device__ __forceinline__ float bf2f(unsigned short h) {
    union { unsigned u; float f; } v; v.u = ((unsigned)h) << 16;
    return v.f;
}
__device__ __forceinline__ unsigned pack_bf2(float a, float b) {
    return ((unsigned)f2bf(a)) | (((unsigned)f2bf(b)) << 16);
}

// ---------------------------------------------------------------------------
// Kernel 1 (merged):
// blocks 0..383: FRAG-MAJOR weight repack. Block = ((l*16+nb)*8+ks); the
//   512 bf16 of one wave-fragment-load stored contiguously: element
//   e = lane*8+j holds W_l[k][n], n = nb*16+(lane&15), k = ks*32+(lane>>4)*8+j.
//   Main-kernel W-frag load = ONE contiguous 1 KB burst at base + ks*1024B.
// blocks 384..447: per-batch A/B (bf16) from the g1 decomposition:
//   A[q] = o[q] @ g1_w[0:26]
//   B[p] = o[p] @ g1_w[26:52] + qst @ g1_w[52:63] + g1_b
// ---------------------------------------------------------------------------
__global__ __launch_bounds__(256) void prep_all(
        const float* __restrict__ x, const float* __restrict__ qst,
        const float* __restrict__ g1_w, const float* __restrict__ g1_b,
        const float* __restrict__ g2_w, const float* __restrict__ g3_w,
        const float* __restrict__ g4_w,
        unsigned short* __restrict__ Abf, unsigned short* __restrict__ Bbf,
        unsigned short* __restrict__ Wt) {
    if (blockIdx.x < 384) {
        int blk = blockIdx.x;
        int ks = blk & 7;
        int nbl = blk >> 3;      // l*16+nb
        int l = nbl >> 4;
        int nb = nbl & 15;
        const float* W = (l == 0) ? g2_w : ((l == 1) ? g3_w : g4_w);
        int t = threadIdx.x;
        #pragma unroll
        for (int u = 0; u < 2; ++u) {
            int e = t + u * 256;             // 0..511
            int lane = e >> 3;
            int j = e & 7;
            int n = nb * 16 + (lane & 15);
            int k = ks * 32 + (lane >> 4) * 8 + j;
            Wt[blk * 512 + e] = f2bf(W[k * HID + n]);
        }
        return;
    }
    int b = blockIdx.x - 384;
    int tid = threadIdx.x;
    __shared__ float o_lds[D2][OBJ];
    for (int idx = tid; idx < 24 * D2; idx += 256) {
        int c = idx >> 6, pos = idx & 63;
        o_lds[pos][c] = x[(b * 24 + c) * D2 + pos];
    }
    if (tid < D2) {
        o_lds[tid][24] = (float)(tid & 7) * (8.0f / 7.0f) - 4.0f;  // cx
        o_lds[tid][25] = (float)(tid >> 3) * (8.0f / 7.0f) - 4.0f; // cy
    }
    __syncthreads();
    int n = tid;  // 0..255
    float qpart = g1_b[n];
    for (int s = 0; s < NQST; ++s)
        qpart += qst[b * NQST + s] * g1_w[(2 * OBJ + s) * HID + n];
    for (int q0 = 0; q0 < D2; q0 += 16) {
        float accA[16], accB[16];
        #pragma unroll
        for (int i = 0; i < 16; ++i) { accA[i] = 0.f; accB[i] = 0.f; }
        for (int c = 0; c < OBJ; ++c) {
            float wA = g1_w[c * HID + n];
            float wB = g1_w[(OBJ + c) * HID + n];
            #pragma unroll
            for (int i = 0; i < 16; ++i) {
                float ov = o_lds[q0 + i][c];
                accA[i] += ov * wA;
                accB[i] += ov * wB;
            }
        }
        #pragma unroll
        for (int i = 0; i < 16; ++i) {
            int q = q0 + i;
            Abf[(b * D2 + q) * HID + n] = f2bf(accA[i]);
            Bbf[(b * D2 + q) * HID + n] = f2bf(accB[i] + qpart);
        }
    }
}

// ---------------------------------------------------------------------------
// rn_main helpers. 256 threads = 4 waves, per-wave n-slice 64.
// h LDS layout: row m at byte m*HSTR, k element K at byte 2K within row.
// No XOR swizzle: padding gives the bank spread, addresses are ks-affine
// (ds_read offset immediates, zero per-ks address VALU).
// ---------------------------------------------------------------------------

// stage h[m][k] = relu(A[m][k] + B[k]) into hb.
__device__ __forceinline__ void stage_h(
        char* hb, const unsigned short* __restrict__ Ab,
        const unsigned short* __restrict__ Bb, int tid) {
    #pragma unroll 2
    for (int i = 0; i < 8; ++i) {
        int c = tid + i * 256;       // 2048 chunks of 8 bf16
        int m = c >> 5;              // 0..63
        int k0 = (c & 31) * 8;
        s16x8 av = *(const s16x8*)(Ab + m * HID + k0);
        s16x8 bv = *(const s16x8*)(Bb + k0);
        s16x8 hv;
        #pragma unroll
        for (int j = 0; j < 8; j += 2) {
            float f0 = bf2f((unsigned short)av[j])     + bf2f((unsigned short)bv[j]);
            float f1 = bf2f((unsigned short)av[j + 1]) + bf2f((unsigned short)bv[j + 1]);
            unsigned w = pack_bf2(fmaxf(f0, 0.f), fmaxf(f1, 0.f));
            hv[j]     = (short)(w & 0xFFFF);
            hv[j + 1] = (short)(w >> 16);
        }
        *(s16x8*)(hb + m * HSTR + k0 * 2) = hv;
    }
}

// layers 0/1: swapped-operand mfma(W,h) -> D[n][m]; bias-in-acc; epilogue
// relu+pack -> OTHER buffer. W: frag-major 1 KB bursts, ks ping-pong
// (wbuf[2][4], 32 regs in flight). setprio(1) around MFMA cluster.
__device__ __forceinline__ void layer_sw(
        const unsigned short* __restrict__ Wl, const float* __restrict__ bias,
        const char* hin, char* hout, int wid, int rg, int col, int lane) {
    const unsigned short* wb0 = Wl + (size_t)(wid * 4 + 0) * 4096 + lane * 8;
    const unsigned short* wb1 = Wl + (size_t)(wid * 4 + 1) * 4096 + lane * 8;
    const unsigned short* wb2 = Wl + (size_t)(wid * 4 + 2) * 4096 + lane * 8;
    const unsigned short* wb3 = Wl + (size_t)(wid * 4 + 3) * 4096 + lane * 8;

    f32x4 acc[4][4];   // [nf][mf]
    #pragma unroll
    for (int nf = 0; nf < 4; ++nf) {
        f32x4 b4 = *(const f32x4*)(bias + wid * 64 + nf * 16 + rg * 4);
        #pragma unroll
        for (int mf = 0; mf < 4; ++mf)
            acc[nf][mf] = b4;               // bias-in-acc
    }

    // per-mf fragment base: affine, computed ONCE; ks -> offset immediate
    const char* hr0 = hin + (0 * 16 + col) * HSTR + rg * 16;
    const char* hr1 = hin + (1 * 16 + col) * HSTR + rg * 16;
    const char* hr2 = hin + (2 * 16 + col) * HSTR + rg * 16;
    const char* hr3 = hin + (3 * 16 + col) * HSTR + rg * 16;

    s16x8 wbuf[2][4];   // ks ping-pong: 32 regs in flight
    wbuf[0][0] = *(const s16x8*)(wb0);
    wbuf[0][1] = *(const s16x8*)(wb1);
    wbuf[0][2] = *(const s16x8*)(wb2);
    wbuf[0][3] = *(const s16x8*)(wb3);

    #pragma unroll
    for (int ks = 0; ks < 8; ++ks) {
        const int cur = ks & 1;
        if (ks < 7) {
            int off = (ks + 1) * 512;
            wbuf[cur ^ 1][0] = *(const s16x8*)(wb0 + off);
            wbuf[cur ^ 1][1] = *(const s16x8*)(wb1 + off);
            wbuf[cur ^ 1][2] = *(const s16x8*)(wb2 + off);
            wbuf[cur ^ 1][3] = *(const s16x8*)(wb3 + off);
        }
        s16x8 hfr[4];
        hfr[0] = *(const s16x8*)(hr0 + ks * 64);
        hfr[1] = *(const s16x8*)(hr1 + ks * 64);
        hfr[2] = *(const s16x8*)(hr2 + ks * 64);
        hfr[3] = *(const s16x8*)(hr3 + ks * 64);
        __builtin_amdgcn_s_setprio(1);
        #pragma unroll
        for (int nf = 0; nf < 4; ++nf)
            #pragma unroll
            for (int mf = 0; mf < 4; ++mf)
                acc[nf][mf] = __builtin_amdgcn_mfma_f32_16x16x32_bf16(
                    wbuf[cur][nf], hfr[mf], acc[nf][mf], 0, 0, 0);
        __builtin_amdgcn_s_setprio(0);
    }
    // epilogue: n = wid*64+nf*16+rg*4+r, m = mf*16+col -> hout
    #pragma unroll
    for (int nf = 0; nf < 4; ++nf) {
        int n0 = wid * 64 + nf * 16 + rg * 4;
        #pragma unroll
        for (int mf = 0; mf < 4; ++mf) {
            int m = mf * 16 + col;
            u32x2 w;
            w[0] = pack_bf2(fmaxf(acc[nf][mf][0], 0.f), fmaxf(acc[nf][mf][1], 0.f));
            w[1] = pack_bf2(fmaxf(acc[nf][mf][2], 0.f), fmaxf(acc[nf][mf][3], 0.f));
            *(u32x2*)(hout + m * HSTR + n0 * 2) = w;
        }
    }
}

// layer 2: unswapped mfma(h,W) -> D[m][n]; bias-in-acc; relu + pair-sum.
__device__ __forceinline__ void layer2_red(
        const unsigned short* __restrict__ Wl, const float* __restrict__ bias,
        const char* hin, float* pacc, int wid, int rg, int col, int lane) {
    const unsigned short* wb0 = Wl + (size_t)(wid * 4 + 0) * 4096 + lane * 8;
    const unsigned short* wb1 = Wl + (size_t)(wid * 4 + 1) * 4096 + lane * 8;
    const unsigned short* wb2 = Wl + (size_t)(wid * 4 + 2) * 4096 + lane * 8;
    const unsigned short* wb3 = Wl + (size_t)(wid * 4 + 3) * 4096 + lane * 8;

    f32x4 acc[4][4];   // [mf][nf]
    #pragma unroll
    for (int nf = 0; nf < 4; ++nf) {
        float bv = bias[wid * 64 + nf * 16 + col];
        f32x4 bb = (f32x4){bv, bv, bv, bv};
        #pragma unroll
        for (int mf = 0; mf < 4; ++mf)
            acc[mf][nf] = bb;
    }

    const char* hr0 = hin + (0 * 16 + col) * HSTR + rg * 16;
    const char* hr1 = hin + (1 * 16 + col) * HSTR + rg * 16;
    const char* hr2 = hin + (2 * 16 + col) * HSTR + rg * 16;
    const char* hr3 = hin + (3 * 16 + col) * HSTR + rg * 16;

    s16x8 wbuf[2][4];
    wbuf[0][0] = *(const s16x8*)(wb0);
    wbuf[0][1] = *(const s16x8*)(wb1);
    wbuf[0][2] = *(const s16x8*)(wb2);
    wbuf[0][3] = *(const s16x8*)(wb3);

    #pragma unroll
    for (int ks = 0; ks < 8; ++ks) {
        const int cur = ks & 1;
        if (ks < 7) {
            int off = (ks + 1) * 512;
            wbuf[cur ^ 1][0] = *(const s16x8*)(wb0 + off);
            wbuf[cur ^ 1][1] = *(const s16x8*)(wb1 + off);
            wbuf[cur ^ 1][2] = *(const s16x8*)(wb2 + off);
            wbuf[cur ^ 1][3] = *(const s16x8*)(wb3 + off);
        }
        s16x8 hfr[4];
        hfr[0] = *(const s16x8*)(hr0 + ks * 64);
        hfr[1] = *(const s16x8*)(hr1 + ks * 64);
        hfr[2] = *(const s16x8*)(hr2 + ks * 64);
        hfr[3] = *(const s16x8*)(hr3 + ks * 64);
        __builtin_amdgcn_s_setprio(1);
        #pragma unroll
        for (int mf = 0; mf < 4; ++mf)
            #pragma unroll
            for (int nf = 0; nf < 4; ++nf)
                acc[mf][nf] = __builtin_amdgcn_mfma_f32_16x16x32_bf16(
                    hfr[mf], wbuf[cur][nf], acc[mf][nf], 0, 0, 0);
        __builtin_amdgcn_s_setprio(0);
    }
    #pragma unroll
    for (int nf = 0; nf < 4; ++nf) {
        float s = 0.f;
        #pragma unroll
        for (int mf = 0; mf < 4; ++mf)
            #pragma unroll
            for (int r = 0; r < 4; ++r)
                s += fmaxf(acc[mf][nf][r], 0.f);
        s += __shfl_xor(s, 16);
        s += __shfl_xor(s, 32);
        pacc[nf] += s;
    }
}

// ---------------------------------------------------------------------------
// Kernel 2: main fused g-network. 256 threads = 4 waves, wave n-slice 64.
// pp LOOP (unroll 1): 3 layer instances instead of 6 -> half the code, so
// the regalloc seam-spill (r13/r14: ~100 MB scratch WRITE) should vanish.
// Padded-stride h (no XOR): bank conflicts ~0, ks-affine LDS addressing.
// 2 x 33 KiB h buffers = 67.6 KiB/WG -> 2 blocks/CU at cap 256.
// ---------------------------------------------------------------------------
__global__ __launch_bounds__(256, 2) void rn_main(
        const unsigned short* __restrict__ Abf, const unsigned short* __restrict__ Bbf,
        const unsigned short* __restrict__ Wt,
        const float* __restrict__ g2_b, const float* __restrict__ g3_b,
        const float* __restrict__ g4_b, float* __restrict__ partial) {
    // XCD-aware swizzle: 2048 WGs, 8 XCDs (2048 % 8 == 0 -> bijective)
    int wg = blockIdx.x;
    int swz = (wg & 7) * 256 + (wg >> 3);
    int b = swz >> 5;
    int t = swz & 31;

    __shared__ __align__(16) char h_all[2 * HBUF];   // 67.6 KiB

    int tid = threadIdx.x;   // 0..255
    int lane = tid & 63;
    int wid = tid >> 6;      // wave 0..3 -> n-slice of 64
    int rg = lane >> 4;      // 0..3
    int col = lane & 15;

    const unsigned short* Ab  = Abf + (size_t)(b * D2) * HID;
    const unsigned short* Bb0 = Bbf + (size_t)(b * D2 + t * 2 + 0) * HID;
    const unsigned short* Bb1 = Bbf + (size_t)(b * D2 + t * 2 + 1) * HID;
    const unsigned short* W0 = Wt;                        // 65536 elems/layer
    const unsigned short* W1 = Wt + (size_t)1 * 65536;
    const unsigned short* W2 = Wt + (size_t)2 * 65536;

    float pacc[4] = {0.f, 0.f, 0.f, 0.f};

    char* hA = h_all;
    char* hB = h_all + HBUF;

    stage_h(hA, Ab, Bb0, tid);
    __syncthreads();                                     // hA ready

    #pragma unroll 1
    for (int pp = 0; pp < 2; ++pp) {
        layer_sw(W0, g2_b, hA, hB, wid, rg, col, lane);  // r hA -> w hB
        __syncthreads();                                 // hB ready, hA free
        layer_sw(W1, g3_b, hB, hA, wid, rg, col, lane);  // r hB -> w hA
        __syncthreads();                                 // hA ready, hB free
        layer2_red(W2, g4_b, hA, pacc, wid, rg, col, lane);  // r hA
        if (pp == 0)
            stage_h(hB, Ab, Bb1, tid);                   // w hB (overlaps L2)
        __syncthreads();                                 // hB staged, hA free
        char* tmp = hA; hA = hB; hB = tmp;
    }

    if (rg == 0) {
        #pragma unroll
        for (int nf = 0; nf < 4; ++nf)
            partial[(size_t)(b * NTILE + t) * HID + wid * 64 + nf * 16 + col]
                = pacc[nf];
    }
}

// ---------------------------------------------------------------------------
// Kernel 3: per-batch reduce over tiles + f-network (fp32) + log_softmax
// ---------------------------------------------------------------------------
__global__ __launch_bounds__(256) void fuse_kernel(
        const float* __restrict__ partial,
        const float* __restrict__ f1_w, const float* __restrict__ f1_b,
        const float* __restrict__ f2_w, const float* __restrict__ f2_b,
        const float* __restrict__ f3_w, const float* __restrict__ f3_b,
        float* __restrict__ out) {
    int b = blockIdx.x;
    int tid = threadIdx.x;
    __shared__ float xg[HID];
    __shared__ float h1[HID];
    __shared__ float h2[HID];
    __shared__ float lred[NOUT];
    __shared__ float lse;

    float s = 0.f;
    for (int t = 0; t < NTILE; ++t)
        s += partial[(size_t)(b * NTILE + t) * HID + tid];
    xg[tid] = s;
    __syncthreads();

    float a1 = f1_b[tid];
    for (int k = 0; k < HID; ++k)
        a1 += xg[k] * f1_w[k * HID + tid];
    h1[tid] = a1 > 0.f ? a1 : 0.f;
    __syncthreads();

    float a2 = f2_b[tid];
    for (int k = 0; k < HID; ++k)
        a2 += h1[k] * f2_w[k * HID + tid];
    h2[tid] = a2 > 0.f ? a2 : 0.f;
    __syncthreads();

    float logit = 0.f;
    if (tid < NOUT) {
        logit = f3_b[tid];
        for (int k = 0; k < HID; ++k)
            logit += h2[k] * f3_w[k * NOUT + tid];
        lred[tid] = logit;
    }
    __syncthreads();
    if (tid == 0) {
        float mx = lred[0];
        for (int j = 1; j < NOUT; ++j) mx = fmaxf(mx, lred[j]);
        float se = 0.f;
        for (int j = 0; j < NOUT; ++j) se += expf(lred[j] - mx);
        lse = mx + logf(se);
    }
    __syncthreads();
    if (tid < NOUT)
        out[b * NOUT + tid] = logit - lse;
}

// ---------------------------------------------------------------------------
extern "C" void kernel_launch(void* const* d_in, const int* in_sizes, int n_in,
                              void* d_out, int out_size, void* d_ws, size_t ws_size,
                              hipStream_t stream) {
    const float* x    = (const float*)d_in[0];
    const float* qst  = (const float*)d_in[1];
    const float* g1_w = (const float*)d_in[2];
    const float* g1_b = (const float*)d_in[3];
    const float* g2_w = (const float*)d_in[4];
    const float* g2_b = (const float*)d_in[5];
    const float* g3_w = (const float*)d_in[6];
    const float* g3_b = (const float*)d_in[7];
    const float* g4_w = (const float*)d_in[8];
    const float* g4_b = (const float*)d_in[9];
    const float* f1_w = (const float*)d_in[10];
    const float* f1_b = (const float*)d_in[11];
    const float* f2_w = (const float*)d_in[12];
    const float* f2_b = (const float*)d_in[13];
    const float* f3_w = (const float*)d_in[14];
    const float* f3_b = (const float*)d_in[15];
    float* out = (float*)d_out;

    char* ws = (char*)d_ws;
    unsigned short* Abf = (unsigned short*)ws;                          // 2 MiB
    unsigned short* Bbf = (unsigned short*)(ws + (2u << 20));           // 2 MiB
    unsigned short* Wt  = (unsigned short*)(ws + (4u << 20));           // 384 KiB
    float* partial      = (float*)(ws + (4u << 20) + (512u << 10));     // 2 MiB

    prep_all<<<384 + NB, 256, 0, stream>>>(x, qst, g1_w, g1_b, g2_w, g3_w, g4_w,
                                           Abf, Bbf, Wt);
    rn_main<<<NB * NTILE, 256, 0, stream>>>(Abf, Bbf, Wt, g2_b, g3_b, g4_b, partial);
    fuse_kernel<<<NB, 256, 0, stream>>>(partial, f1_w, f1_b, f2_w, f2_b, f3_w, f3_b, out);
}

// Round 16
// 163.992 us; speedup vs baseline: 3.1845x; 3.1845x over previous
//
#include <hip/hip_runtime.h>
#include <hip/hip_bf16.h>
#include <math.h>

#define NB   64      // batch
#define D2   64      // objects per batch
#define OBJ  26      // K+2 features per object
#define NQST 11
#define HID  256
#define NOUT 28
#define NTILE 32     // p-tiles per batch (2 p's each, processed sequentially)

typedef __attribute__((ext_vector_type(8))) short s16x8;
typedef __attribute__((ext_vector_type(4))) float f32x4;
typedef __attribute__((ext_vector_type(2))) unsigned int u32x2;

__device__ __forceinline__ unsigned short f2bf(float f) {
    __hip_bfloat16 h = __float2bfloat16(f);
    union { __hip_bfloat16 h; unsigned short u; } v; v.h = h; return v.u;
}
__device__ __forceinline__ float bf2f(unsigned short h) {
    union { unsigned u; float f; } v; v.u = ((unsigned)h) << 16;
    return v.f;
}
__device__ __forceinline__ unsigned pack_bf2(float a, float b) {
    return ((unsigned)f2bf(a)) | (((unsigned)f2bf(b)) << 16);
}

// ---------------------------------------------------------------------------
// Kernel 1 (merged):
// blocks 0..383: FRAG-MAJOR weight repack. Block = ((l*16+nb)*8+ks); the
//   512 bf16 of one wave-fragment-load stored contiguously: element
//   e = lane*8+j holds W_l[k][n], n = nb*16+(lane&15), k = ks*32+(lane>>4)*8+j.
//   Main-kernel W-frag load = ONE contiguous 1 KB burst at base + ks*1024B.
// blocks 384..447: per-batch A/B (bf16) from the g1 decomposition:
//   A[q] = o[q] @ g1_w[0:26]
//   B[p] = o[p] @ g1_w[26:52] + qst @ g1_w[52:63] + g1_b
// ---------------------------------------------------------------------------
__global__ __launch_bounds__(256) void prep_all(
        const float* __restrict__ x, const float* __restrict__ qst,
        const float* __restrict__ g1_w, const float* __restrict__ g1_b,
        const float* __restrict__ g2_w, const float* __restrict__ g3_w,
        const float* __restrict__ g4_w,
        unsigned short* __restrict__ Abf, unsigned short* __restrict__ Bbf,
        unsigned short* __restrict__ Wt) {
    if (blockIdx.x < 384) {
        int blk = blockIdx.x;
        int ks = blk & 7;
        int nbl = blk >> 3;      // l*16+nb
        int l = nbl >> 4;
        int nb = nbl & 15;
        const float* W = (l == 0) ? g2_w : ((l == 1) ? g3_w : g4_w);
        int t = threadIdx.x;
        #pragma unroll
        for (int u = 0; u < 2; ++u) {
            int e = t + u * 256;             // 0..511
            int lane = e >> 3;
            int j = e & 7;
            int n = nb * 16 + (lane & 15);
            int k = ks * 32 + (lane >> 4) * 8 + j;
            Wt[blk * 512 + e] = f2bf(W[k * HID + n]);
        }
        return;
    }
    int b = blockIdx.x - 384;
    int tid = threadIdx.x;
    __shared__ float o_lds[D2][OBJ];
    for (int idx = tid; idx < 24 * D2; idx += 256) {
        int c = idx >> 6, pos = idx & 63;
        o_lds[pos][c] = x[(b * 24 + c) * D2 + pos];
    }
    if (tid < D2) {
        o_lds[tid][24] = (float)(tid & 7) * (8.0f / 7.0f) - 4.0f;  // cx
        o_lds[tid][25] = (float)(tid >> 3) * (8.0f / 7.0f) - 4.0f; // cy
    }
    __syncthreads();
    int n = tid;  // 0..255
    float qpart = g1_b[n];
    for (int s = 0; s < NQST; ++s)
        qpart += qst[b * NQST + s] * g1_w[(2 * OBJ + s) * HID + n];
    for (int q0 = 0; q0 < D2; q0 += 16) {
        float accA[16], accB[16];
        #pragma unroll
        for (int i = 0; i < 16; ++i) { accA[i] = 0.f; accB[i] = 0.f; }
        for (int c = 0; c < OBJ; ++c) {
            float wA = g1_w[c * HID + n];
            float wB = g1_w[(OBJ + c) * HID + n];
            #pragma unroll
            for (int i = 0; i < 16; ++i) {
                float ov = o_lds[q0 + i][c];
                accA[i] += ov * wA;
                accB[i] += ov * wB;
            }
        }
        #pragma unroll
        for (int i = 0; i < 16; ++i) {
            int q = q0 + i;
            Abf[(b * D2 + q) * HID + n] = f2bf(accA[i]);
            Bbf[(b * D2 + q) * HID + n] = f2bf(accB[i] + qpart);
        }
    }
}

// ---------------------------------------------------------------------------
// rn_main helpers. 256 threads = 4 waves, per-wave n-slice 64.
// ---------------------------------------------------------------------------

// stage h[m][k] = relu(A[m][k] + B[k]) into hbuf (swizzled).
__device__ __forceinline__ void stage_h(
        unsigned short* hbuf, const unsigned short* __restrict__ Ab,
        const unsigned short* __restrict__ Bb, int tid) {
    #pragma unroll 2
    for (int i = 0; i < 8; ++i) {
        int c = tid + i * 256;       // 2048 chunks of 8 bf16
        int m = c >> 5;              // 0..63
        int k0 = (c & 31) * 8;
        s16x8 av = *(const s16x8*)(Ab + m * HID + k0);
        s16x8 bv = *(const s16x8*)(Bb + k0);
        s16x8 hv;
        #pragma unroll
        for (int j = 0; j < 8; j += 2) {
            float f0 = bf2f((unsigned short)av[j])     + bf2f((unsigned short)bv[j]);
            float f1 = bf2f((unsigned short)av[j + 1]) + bf2f((unsigned short)bv[j + 1]);
            unsigned w = pack_bf2(fmaxf(f0, 0.f), fmaxf(f1, 0.f));
            hv[j]     = (short)(w & 0xFFFF);
            hv[j + 1] = (short)(w >> 16);
        }
        int byte = (m * 512 + k0 * 2) ^ ((m & 7) << 4);
        *(s16x8*)((char*)hbuf + byte) = hv;
    }
}

// layers 0/1: swapped-operand mfma(W,h) -> D[n][m]; bias-in-acc; epilogue
// relu+pack -> OTHER buffer. W: frag-major bursts, ks-granularity ping-pong
// (wbuf[2][4] = 32 regs in flight; one ks's 16-MFMA cluster ~310 cyc/SIMD
// >= L2 latency). setprio(1) around MFMA cluster.
__device__ __forceinline__ void layer_sw(
        const unsigned short* __restrict__ Wl, const float* __restrict__ bias,
        const unsigned short* hin, unsigned short* hout,
        int wid, int rg, int col, int lane) {
    const unsigned short* wb0 = Wl + (size_t)(wid * 4 + 0) * 4096 + lane * 8;
    const unsigned short* wb1 = Wl + (size_t)(wid * 4 + 1) * 4096 + lane * 8;
    const unsigned short* wb2 = Wl + (size_t)(wid * 4 + 2) * 4096 + lane * 8;
    const unsigned short* wb3 = Wl + (size_t)(wid * 4 + 3) * 4096 + lane * 8;

    f32x4 acc[4][4];   // [nf][mf]
    #pragma unroll
    for (int nf = 0; nf < 4; ++nf) {
        f32x4 b4 = *(const f32x4*)(bias + wid * 64 + nf * 16 + rg * 4);
        #pragma unroll
        for (int mf = 0; mf < 4; ++mf)
            acc[nf][mf] = b4;               // bias-in-acc
    }

    s16x8 wbuf[2][4];   // ks ping-pong: 32 regs in flight
    wbuf[0][0] = *(const s16x8*)(wb0);
    wbuf[0][1] = *(const s16x8*)(wb1);
    wbuf[0][2] = *(const s16x8*)(wb2);
    wbuf[0][3] = *(const s16x8*)(wb3);

    #pragma unroll
    for (int ks = 0; ks < 8; ++ks) {
        const int cur = ks & 1;
        if (ks < 7) {
            int off = (ks + 1) * 512;
            wbuf[cur ^ 1][0] = *(const s16x8*)(wb0 + off);
            wbuf[cur ^ 1][1] = *(const s16x8*)(wb1 + off);
            wbuf[cur ^ 1][2] = *(const s16x8*)(wb2 + off);
            wbuf[cur ^ 1][3] = *(const s16x8*)(wb3 + off);
        }
        int ko = ks * 32 + rg * 8;
        s16x8 hfr[4];
        #pragma unroll
        for (int mf = 0; mf < 4; ++mf) {
            int m = mf * 16 + col;
            int byte = (m * 512 + ko * 2) ^ ((m & 7) << 4);
            hfr[mf] = *(const s16x8*)((const char*)hin + byte);
        }
        __builtin_amdgcn_s_setprio(1);
        #pragma unroll
        for (int nf = 0; nf < 4; ++nf)
            #pragma unroll
            for (int mf = 0; mf < 4; ++mf)
                acc[nf][mf] = __builtin_amdgcn_mfma_f32_16x16x32_bf16(
                    wbuf[cur][nf], hfr[mf], acc[nf][mf], 0, 0, 0);
        __builtin_amdgcn_s_setprio(0);
    }
    // epilogue: n = wid*64+nf*16+rg*4+r, m = mf*16+col -> hout
    #pragma unroll
    for (int nf = 0; nf < 4; ++nf) {
        int n0 = wid * 64 + nf * 16 + rg * 4;
        #pragma unroll
        for (int mf = 0; mf < 4; ++mf) {
            int m = mf * 16 + col;
            u32x2 w;
            w[0] = pack_bf2(fmaxf(acc[nf][mf][0], 0.f), fmaxf(acc[nf][mf][1], 0.f));
            w[1] = pack_bf2(fmaxf(acc[nf][mf][2], 0.f), fmaxf(acc[nf][mf][3], 0.f));
            int byte = (m * 512 + n0 * 2) ^ ((m & 7) << 4);
            *(u32x2*)((char*)hout + byte) = w;
        }
    }
}

// layer 2: unswapped mfma(h,W) -> D[m][n]; bias-in-acc; relu + pair-sum.
// Same frag-major ks ping-pong + setprio.
__device__ __forceinline__ void layer2_red(
        const unsigned short* __restrict__ Wl, const float* __restrict__ bias,
        const unsigned short* hin, float* pacc, int wid, int rg, int col, int lane) {
    const unsigned short* wb0 = Wl + (size_t)(wid * 4 + 0) * 4096 + lane * 8;
    const unsigned short* wb1 = Wl + (size_t)(wid * 4 + 1) * 4096 + lane * 8;
    const unsigned short* wb2 = Wl + (size_t)(wid * 4 + 2) * 4096 + lane * 8;
    const unsigned short* wb3 = Wl + (size_t)(wid * 4 + 3) * 4096 + lane * 8;

    f32x4 acc[4][4];   // [mf][nf]
    #pragma unroll
    for (int nf = 0; nf < 4; ++nf) {
        float bv = bias[wid * 64 + nf * 16 + col];
        f32x4 bb = (f32x4){bv, bv, bv, bv};
        #pragma unroll
        for (int mf = 0; mf < 4; ++mf)
            acc[mf][nf] = bb;
    }

    s16x8 wbuf[2][4];
    wbuf[0][0] = *(const s16x8*)(wb0);
    wbuf[0][1] = *(const s16x8*)(wb1);
    wbuf[0][2] = *(const s16x8*)(wb2);
    wbuf[0][3] = *(const s16x8*)(wb3);

    #pragma unroll
    for (int ks = 0; ks < 8; ++ks) {
        const int cur = ks & 1;
        if (ks < 7) {
            int off = (ks + 1) * 512;
            wbuf[cur ^ 1][0] = *(const s16x8*)(wb0 + off);
            wbuf[cur ^ 1][1] = *(const s16x8*)(wb1 + off);
            wbuf[cur ^ 1][2] = *(const s16x8*)(wb2 + off);
            wbuf[cur ^ 1][3] = *(const s16x8*)(wb3 + off);
        }
        int ko = ks * 32 + rg * 8;
        s16x8 hfr[4];
        #pragma unroll
        for (int mf = 0; mf < 4; ++mf) {
            int m = mf * 16 + col;
            int byte = (m * 512 + ko * 2) ^ ((m & 7) << 4);
            hfr[mf] = *(const s16x8*)((const char*)hin + byte);
        }
        __builtin_amdgcn_s_setprio(1);
        #pragma unroll
        for (int mf = 0; mf < 4; ++mf)
            #pragma unroll
            for (int nf = 0; nf < 4; ++nf)
                acc[mf][nf] = __builtin_amdgcn_mfma_f32_16x16x32_bf16(
                    hfr[mf], wbuf[cur][nf], acc[mf][nf], 0, 0, 0);
        __builtin_amdgcn_s_setprio(0);
    }
    #pragma unroll
    for (int nf = 0; nf < 4; ++nf) {
        float s = 0.f;
        #pragma unroll
        for (int mf = 0; mf < 4; ++mf)
            #pragma unroll
            for (int r = 0; r < 4; ++r)
                s += fmaxf(acc[mf][nf][r], 0.f);
        s += __shfl_xor(s, 16);
        s += __shfl_xor(s, 32);
        pacc[nf] += s;
    }
}

// ---------------------------------------------------------------------------
// Kernel 2: main fused g-network — EXACT r13 structure (133 us champion),
// single change: __launch_bounds__(256, 1). Rationale: occupancy is
// LDS-bound at 2 blocks/CU (2x32 KiB h); waves/SIMD = floor(512/regs), so
// any allocation <= 256 keeps identical residency, while the old (256,2)
// cap forced ~48 dwords/thread of scratch (100 MB WRITE). Cap 512 lets the
// allocator settle spill-free (~200-230 regs expected).
// ---------------------------------------------------------------------------
__global__ __launch_bounds__(256, 1) void rn_main(
        const unsigned short* __restrict__ Abf, const unsigned short* __restrict__ Bbf,
        const unsigned short* __restrict__ Wt,
        const float* __restrict__ g2_b, const float* __restrict__ g3_b,
        const float* __restrict__ g4_b, float* __restrict__ partial) {
    // XCD-aware swizzle: 2048 WGs, 8 XCDs (2048 % 8 == 0 -> bijective)
    int wg = blockIdx.x;
    int swz = (wg & 7) * 256 + (wg >> 3);
    int b = swz >> 5;
    int t = swz & 31;

    __shared__ unsigned short h0[D2 * HID];   // 32 KiB
    __shared__ unsigned short h1[D2 * HID];   // 32 KiB

    int tid = threadIdx.x;   // 0..255
    int lane = tid & 63;
    int wid = tid >> 6;      // wave 0..3 -> n-slice of 64
    int rg = lane >> 4;      // 0..3
    int col = lane & 15;

    const unsigned short* Ab  = Abf + (size_t)(b * D2) * HID;
    const unsigned short* Bb0 = Bbf + (size_t)(b * D2 + t * 2 + 0) * HID;
    const unsigned short* Bb1 = Bbf + (size_t)(b * D2 + t * 2 + 1) * HID;
    const unsigned short* W0 = Wt;                        // 65536 elems/layer
    const unsigned short* W1 = Wt + (size_t)1 * 65536;
    const unsigned short* W2 = Wt + (size_t)2 * 65536;

    float pacc[4] = {0.f, 0.f, 0.f, 0.f};

    // ---- pp0 ----
    stage_h(h0, Ab, Bb0, tid);
    __syncthreads();                                         // h0 ready
    layer_sw(W0, g2_b, h0, h1, wid, rg, col, lane);          // r h0 -> w h1
    __syncthreads();                                         // h1 ready
    layer_sw(W1, g3_b, h1, h0, wid, rg, col, lane);          // r h1 -> w h0
    __syncthreads();                                         // h0 ready
    layer2_red(W2, g4_b, h0, pacc, wid, rg, col, lane);      // r h0
    stage_h(h1, Ab, Bb1, tid);                               // w h1 (overlaps)
    __syncthreads();                                         // h1 ready

    // ---- pp1 (buffers flipped) ----
    layer_sw(W0, g2_b, h1, h0, wid, rg, col, lane);
    __syncthreads();
    layer_sw(W1, g3_b, h0, h1, wid, rg, col, lane);
    __syncthreads();
    layer2_red(W2, g4_b, h1, pacc, wid, rg, col, lane);

    if (rg == 0) {
        #pragma unroll
        for (int nf = 0; nf < 4; ++nf)
            partial[(size_t)(b * NTILE + t) * HID + wid * 64 + nf * 16 + col]
                = pacc[nf];
    }
}

// ---------------------------------------------------------------------------
// Kernel 3: per-batch reduce over tiles + f-network (fp32) + log_softmax
// ---------------------------------------------------------------------------
__global__ __launch_bounds__(256) void fuse_kernel(
        const float* __restrict__ partial,
        const float* __restrict__ f1_w, const float* __restrict__ f1_b,
        const float* __restrict__ f2_w, const float* __restrict__ f2_b,
        const float* __restrict__ f3_w, const float* __restrict__ f3_b,
        float* __restrict__ out) {
    int b = blockIdx.x;
    int tid = threadIdx.x;
    __shared__ float xg[HID];
    __shared__ float h1[HID];
    __shared__ float h2[HID];
    __shared__ float lred[NOUT];
    __shared__ float lse;

    float s = 0.f;
    for (int t = 0; t < NTILE; ++t)
        s += partial[(size_t)(b * NTILE + t) * HID + tid];
    xg[tid] = s;
    __syncthreads();

    float a1 = f1_b[tid];
    for (int k = 0; k < HID; ++k)
        a1 += xg[k] * f1_w[k * HID + tid];
    h1[tid] = a1 > 0.f ? a1 : 0.f;
    __syncthreads();

    float a2 = f2_b[tid];
    for (int k = 0; k < HID; ++k)
        a2 += h1[k] * f2_w[k * HID + tid];
    h2[tid] = a2 > 0.f ? a2 : 0.f;
    __syncthreads();

    float logit = 0.f;
    if (tid < NOUT) {
        logit = f3_b[tid];
        for (int k = 0; k < HID; ++k)
            logit += h2[k] * f3_w[k * NOUT + tid];
        lred[tid] = logit;
    }
    __syncthreads();
    if (tid == 0) {
        float mx = lred[0];
        for (int j = 1; j < NOUT; ++j) mx = fmaxf(mx, lred[j]);
        float se = 0.f;
        for (int j = 0; j < NOUT; ++j) se += expf(lred[j] - mx);
        lse = mx + logf(se);
    }
    __syncthreads();
    if (tid < NOUT)
        out[b * NOUT + tid] = logit - lse;
}

// ---------------------------------------------------------------------------
extern "C" void kernel_launch(void* const* d_in, const int* in_sizes, int n_in,
                              void* d_out, int out_size, void* d_ws, size_t ws_size,
                              hipStream_t stream) {
    const float* x    = (const float*)d_in[0];
    const float* qst  = (const float*)d_in[1];
    const float* g1_w = (const float*)d_in[2];
    const float* g1_b = (const float*)d_in[3];
    const float* g2_w = (const float*)d_in[4];
    const float* g2_b = (const float*)d_in[5];
    const float* g3_w = (const float*)d_in[6];
    const float* g3_b = (const float*)d_in[7];
    const float* g4_w = (const float*)d_in[8];
    const float* g4_b = (const float*)d_in[9];
    const float* f1_w = (const float*)d_in[10];
    const float* f1_b = (const float*)d_in[11];
    const float* f2_w = (const float*)d_in[12];
    const float* f2_b = (const float*)d_in[13];
    const float* f3_w = (const float*)d_in[14];
    const float* f3_b = (const float*)d_in[15];
    float* out = (float*)d_out;

    char* ws = (char*)d_ws;
    unsigned short* Abf = (unsigned short*)ws;                          // 2 MiB
    unsigned short* Bbf = (unsigned short*)(ws + (2u << 20));           // 2 MiB
    unsigned short* Wt  = (unsigned short*)(ws + (4u << 20));           // 384 KiB
    float* partial      = (float*)(ws + (4u << 20) + (512u << 10));     // 2 MiB

    prep_all<<<384 + NB, 256, 0, stream>>>(x, qst, g1_w, g1_b, g2_w, g3_w, g4_w,
                                           Abf, Bbf, Wt);
    rn_main<<<NB * NTILE, 256, 0, stream>>>(Abf, Bbf, Wt, g2_b, g3_b, g4_b, partial);
    fuse_kernel<<<NB, 256, 0, stream>>>(partial, f1_w, f1_b, f2_w, f2_b, f3_w, f3_b, out);
}

// Round 18
// 159.842 us; speedup vs baseline: 3.2671x; 1.0260x over previous
//
#include <hip/hip_runtime.h>
#include <hip/hip_bf16.h>
#include <math.h>

#define NB   64      // batch
#define D2   64      // objects per batch
#define OBJ  26      // K+2 features per object
#define NQST 11
#define HID  256
#define NOUT 28
#define NTILE 32     // p-tiles per batch (2 p's each, processed sequentially)

typedef _Float16 f16x8 __attribute__((ext_vector_type(8)));
typedef __attribute__((ext_vector_type(4))) float f32x4;
typedef __attribute__((ext_vector_type(2))) unsigned int u32x2;

__device__ __forceinline__ unsigned pack_h2(float a, float b) {
    auto r = __builtin_amdgcn_cvt_pkrtz(a, b);   // v_cvt_pkrtz_f16_f32
    union U { decltype(r) h; unsigned u; } v;
    v.h = r;
    return v.u;
}
__device__ __forceinline__ f16x8 relu8(f16x8 x) {
    f16x8 z = {0, 0, 0, 0, 0, 0, 0, 0};
#if __has_builtin(__builtin_elementwise_max)
    return __builtin_elementwise_max(x, z);    // v_pk_max_f16 x4
#else
    #pragma unroll
    for (int j = 0; j < 8; ++j) x[j] = x[j] > (_Float16)0 ? x[j] : (_Float16)0;
    return x;
#endif
}

// ---------------------------------------------------------------------------
// Kernel 1 (merged):
// blocks 0..383: FRAG-MAJOR weight repack (fp16). Block = ((l*16+nb)*8+ks);
//   element e = lane*8+j holds W_l[k][n], n = nb*16+(lane&15),
//   k = ks*32+(lane>>4)*8+j. Main-kernel W-frag load = ONE contiguous 1 KB
//   burst at base + ks*1024B.
// blocks 384..447: per-batch A/B (fp16) from the g1 decomposition:
//   A[q] = o[q] @ g1_w[0:26]
//   B[p] = o[p] @ g1_w[26:52] + qst @ g1_w[52:63] + g1_b
// ---------------------------------------------------------------------------
__global__ __launch_bounds__(256) void prep_all(
        const float* __restrict__ x, const float* __restrict__ qst,
        const float* __restrict__ g1_w, const float* __restrict__ g1_b,
        const float* __restrict__ g2_w, const float* __restrict__ g3_w,
        const float* __restrict__ g4_w,
        _Float16* __restrict__ Abf, _Float16* __restrict__ Bbf,
        _Float16* __restrict__ Wt) {
    if (blockIdx.x < 384) {
        int blk = blockIdx.x;
        int ks = blk & 7;
        int nbl = blk >> 3;      // l*16+nb
        int l = nbl >> 4;
        int nb = nbl & 15;
        const float* W = (l == 0) ? g2_w : ((l == 1) ? g3_w : g4_w);
        int t = threadIdx.x;
        #pragma unroll
        for (int u = 0; u < 2; ++u) {
            int e = t + u * 256;             // 0..511
            int lane = e >> 3;
            int j = e & 7;
            int n = nb * 16 + (lane & 15);
            int k = ks * 32 + (lane >> 4) * 8 + j;
            Wt[blk * 512 + e] = (_Float16)W[k * HID + n];
        }
        return;
    }
    int b = blockIdx.x - 384;
    int tid = threadIdx.x;
    __shared__ float o_lds[D2][OBJ];
    for (int idx = tid; idx < 24 * D2; idx += 256) {
        int c = idx >> 6, pos = idx & 63;
        o_lds[pos][c] = x[(b * 24 + c) * D2 + pos];
    }
    if (tid < D2) {
        o_lds[tid][24] = (float)(tid & 7) * (8.0f / 7.0f) - 4.0f;  // cx
        o_lds[tid][25] = (float)(tid >> 3) * (8.0f / 7.0f) - 4.0f; // cy
    }
    __syncthreads();
    int n = tid;  // 0..255
    float qpart = g1_b[n];
    for (int s = 0; s < NQST; ++s)
        qpart += qst[b * NQST + s] * g1_w[(2 * OBJ + s) * HID + n];
    for (int q0 = 0; q0 < D2; q0 += 16) {
        float accA[16], accB[16];
        #pragma unroll
        for (int i = 0; i < 16; ++i) { accA[i] = 0.f; accB[i] = 0.f; }
        for (int c = 0; c < OBJ; ++c) {
            float wA = g1_w[c * HID + n];
            float wB = g1_w[(OBJ + c) * HID + n];
            #pragma unroll
            for (int i = 0; i < 16; ++i) {
                float ov = o_lds[q0 + i][c];
                accA[i] += ov * wA;
                accB[i] += ov * wB;
            }
        }
        #pragma unroll
        for (int i = 0; i < 16; ++i) {
            int q = q0 + i;
            Abf[(b * D2 + q) * HID + n] = (_Float16)accA[i];
            Bbf[(b * D2 + q) * HID + n] = (_Float16)(accB[i] + qpart);
        }
    }
}

// ---------------------------------------------------------------------------
// rn_main helpers. 256 threads = 4 waves, per-wave n-slice 64.
// fp16 datapath: packed v_pk_add_f16 / v_pk_max_f16 staging, fp16 MFMA
// (same rate as bf16, more mantissa bits), f32 accumulation.
// ---------------------------------------------------------------------------

// stage h[m][k] = relu(A[m][k] + B[k]) into hbuf (swizzled).
__device__ __forceinline__ void stage_h(
        _Float16* hbuf, const _Float16* __restrict__ Ab,
        const _Float16* __restrict__ Bb, int tid) {
    #pragma unroll 2
    for (int i = 0; i < 8; ++i) {
        int c = tid + i * 256;       // 2048 chunks of 8 fp16
        int m = c >> 5;              // 0..63
        int k0 = (c & 31) * 8;
        f16x8 av = *(const f16x8*)(Ab + m * HID + k0);
        f16x8 bv = *(const f16x8*)(Bb + k0);
        f16x8 hv = relu8(av + bv);   // 4x pk_add + 4x pk_max
        int byte = (m * 512 + k0 * 2) ^ ((m & 7) << 4);
        *(f16x8*)((char*)hbuf + byte) = hv;
    }
}

// layers 0/1: swapped-operand mfma(W,h) -> D[n][m]; bias-in-acc; epilogue
// relu+pack -> OTHER buffer. W: frag-major bursts, ks-granularity ping-pong
// (wbuf[2][4] = 32 regs in flight; one ks's 16-MFMA cluster ~310 cyc/SIMD
// >= L2 latency). setprio(1) around MFMA cluster.
__device__ __forceinline__ void layer_sw(
        const _Float16* __restrict__ Wl, const float* __restrict__ bias,
        const _Float16* hin, _Float16* hout,
        int wid, int rg, int col, int lane) {
    const _Float16* wb0 = Wl + (size_t)(wid * 4 + 0) * 4096 + lane * 8;
    const _Float16* wb1 = Wl + (size_t)(wid * 4 + 1) * 4096 + lane * 8;
    const _Float16* wb2 = Wl + (size_t)(wid * 4 + 2) * 4096 + lane * 8;
    const _Float16* wb3 = Wl + (size_t)(wid * 4 + 3) * 4096 + lane * 8;

    f32x4 acc[4][4];   // [nf][mf]
    #pragma unroll
    for (int nf = 0; nf < 4; ++nf) {
        f32x4 b4 = *(const f32x4*)(bias + wid * 64 + nf * 16 + rg * 4);
        #pragma unroll
        for (int mf = 0; mf < 4; ++mf)
            acc[nf][mf] = b4;               // bias-in-acc
    }

    f16x8 wbuf[2][4];   // ks ping-pong: 32 regs in flight
    wbuf[0][0] = *(const f16x8*)(wb0);
    wbuf[0][1] = *(const f16x8*)(wb1);
    wbuf[0][2] = *(const f16x8*)(wb2);
    wbuf[0][3] = *(const f16x8*)(wb3);

    #pragma unroll
    for (int ks = 0; ks < 8; ++ks) {
        const int cur = ks & 1;
        if (ks < 7) {
            int off = (ks + 1) * 512;
            wbuf[cur ^ 1][0] = *(const f16x8*)(wb0 + off);
            wbuf[cur ^ 1][1] = *(const f16x8*)(wb1 + off);
            wbuf[cur ^ 1][2] = *(const f16x8*)(wb2 + off);
            wbuf[cur ^ 1][3] = *(const f16x8*)(wb3 + off);
        }
        int ko = ks * 32 + rg * 8;
        f16x8 hfr[4];
        #pragma unroll
        for (int mf = 0; mf < 4; ++mf) {
            int m = mf * 16 + col;
            int byte = (m * 512 + ko * 2) ^ ((m & 7) << 4);
            hfr[mf] = *(const f16x8*)((const char*)hin + byte);
        }
        __builtin_amdgcn_s_setprio(1);
        #pragma unroll
        for (int nf = 0; nf < 4; ++nf)
            #pragma unroll
            for (int mf = 0; mf < 4; ++mf)
                acc[nf][mf] = __builtin_amdgcn_mfma_f32_16x16x32_f16(
                    wbuf[cur][nf], hfr[mf], acc[nf][mf], 0, 0, 0);
        __builtin_amdgcn_s_setprio(0);
    }
    // epilogue: n = wid*64+nf*16+rg*4+r, m = mf*16+col -> hout
    #pragma unroll
    for (int nf = 0; nf < 4; ++nf) {
        int n0 = wid * 64 + nf * 16 + rg * 4;
        #pragma unroll
        for (int mf = 0; mf < 4; ++mf) {
            int m = mf * 16 + col;
            u32x2 w;
            w[0] = pack_h2(fmaxf(acc[nf][mf][0], 0.f), fmaxf(acc[nf][mf][1], 0.f));
            w[1] = pack_h2(fmaxf(acc[nf][mf][2], 0.f), fmaxf(acc[nf][mf][3], 0.f));
            int byte = (m * 512 + n0 * 2) ^ ((m & 7) << 4);
            *(u32x2*)((char*)hout + byte) = w;
        }
    }
}

// layer 2: unswapped mfma(h,W) -> D[m][n]; bias-in-acc; relu + pair-sum.
// Same frag-major ks ping-pong + setprio.
__device__ __forceinline__ void layer2_red(
        const _Float16* __restrict__ Wl, const float* __restrict__ bias,
        const _Float16* hin, float* pacc, int wid, int rg, int col, int lane) {
    const _Float16* wb0 = Wl + (size_t)(wid * 4 + 0) * 4096 + lane * 8;
    const _Float16* wb1 = Wl + (size_t)(wid * 4 + 1) * 4096 + lane * 8;
    const _Float16* wb2 = Wl + (size_t)(wid * 4 + 2) * 4096 + lane * 8;
    const _Float16* wb3 = Wl + (size_t)(wid * 4 + 3) * 4096 + lane * 8;

    f32x4 acc[4][4];   // [mf][nf]
    #pragma unroll
    for (int nf = 0; nf < 4; ++nf) {
        float bv = bias[wid * 64 + nf * 16 + col];
        f32x4 bb = (f32x4){bv, bv, bv, bv};
        #pragma unroll
        for (int mf = 0; mf < 4; ++mf)
            acc[mf][nf] = bb;
    }

    f16x8 wbuf[2][4];
    wbuf[0][0] = *(const f16x8*)(wb0);
    wbuf[0][1] = *(const f16x8*)(wb1);
    wbuf[0][2] = *(const f16x8*)(wb2);
    wbuf[0][3] = *(const f16x8*)(wb3);

    #pragma unroll
    for (int ks = 0; ks < 8; ++ks) {
        const int cur = ks & 1;
        if (ks < 7) {
            int off = (ks + 1) * 512;
            wbuf[cur ^ 1][0] = *(const f16x8*)(wb0 + off);
            wbuf[cur ^ 1][1] = *(const f16x8*)(wb1 + off);
            wbuf[cur ^ 1][2] = *(const f16x8*)(wb2 + off);
            wbuf[cur ^ 1][3] = *(const f16x8*)(wb3 + off);
        }
        int ko = ks * 32 + rg * 8;
        f16x8 hfr[4];
        #pragma unroll
        for (int mf = 0; mf < 4; ++mf) {
            int m = mf * 16 + col;
            int byte = (m * 512 + ko * 2) ^ ((m & 7) << 4);
            hfr[mf] = *(const f16x8*)((const char*)hin + byte);
        }
        __builtin_amdgcn_s_setprio(1);
        #pragma unroll
        for (int mf = 0; mf < 4; ++mf)
            #pragma unroll
            for (int nf = 0; nf < 4; ++nf)
                acc[mf][nf] = __builtin_amdgcn_mfma_f32_16x16x32_f16(
                    hfr[mf], wbuf[cur][nf], acc[mf][nf], 0, 0, 0);
        __builtin_amdgcn_s_setprio(0);
    }
    #pragma unroll
    for (int nf = 0; nf < 4; ++nf) {
        float s = 0.f;
        #pragma unroll
        for (int mf = 0; mf < 4; ++mf)
            #pragma unroll
            for (int r = 0; r < 4; ++r)
                s += fmaxf(acc[mf][nf][r], 0.f);
        s += __shfl_xor(s, 16);
        s += __shfl_xor(s, 32);
        pacc[nf] += s;
    }
}

// ---------------------------------------------------------------------------
// Kernel 2: main fused g-network — EXACT r13 structure + fp16 datapath.
// 256 threads = 4 waves, wave n-slice 64, double-buffered h (2x32 KiB),
// 6 barriers per WG, launch_bounds(256,2): 2 blocks/CU (the (256,1)
// experiment r16 killed the spill but halved residency -> SLOWER; the
// ~100 MB scratch is L2-absorbed and cheap, residency is what matters).
// ---------------------------------------------------------------------------
__global__ __launch_bounds__(256, 2) void rn_main(
        const _Float16* __restrict__ Abf, const _Float16* __restrict__ Bbf,
        const _Float16* __restrict__ Wt,
        const float* __restrict__ g2_b, const float* __restrict__ g3_b,
        const float* __restrict__ g4_b, float* __restrict__ partial) {
    // XCD-aware swizzle: 2048 WGs, 8 XCDs (2048 % 8 == 0 -> bijective)
    int wg = blockIdx.x;
    int swz = (wg & 7) * 256 + (wg >> 3);
    int b = swz >> 5;
    int t = swz & 31;

    __shared__ _Float16 h0[D2 * HID];   // 32 KiB
    __shared__ _Float16 h1[D2 * HID];   // 32 KiB

    int tid = threadIdx.x;   // 0..255
    int lane = tid & 63;
    int wid = tid >> 6;      // wave 0..3 -> n-slice of 64
    int rg = lane >> 4;      // 0..3
    int col = lane & 15;

    const _Float16* Ab  = Abf + (size_t)(b * D2) * HID;
    const _Float16* Bb0 = Bbf + (size_t)(b * D2 + t * 2 + 0) * HID;
    const _Float16* Bb1 = Bbf + (size_t)(b * D2 + t * 2 + 1) * HID;
    const _Float16* W0 = Wt;                        // 65536 elems/layer
    const _Float16* W1 = Wt + (size_t)1 * 65536;
    const _Float16* W2 = Wt + (size_t)2 * 65536;

    float pacc[4] = {0.f, 0.f, 0.f, 0.f};

    // ---- pp0 ----
    stage_h(h0, Ab, Bb0, tid);
    __syncthreads();                                         // h0 ready
    layer_sw(W0, g2_b, h0, h1, wid, rg, col, lane);          // r h0 -> w h1
    __syncthreads();                                         // h1 ready
    layer_sw(W1, g3_b, h1, h0, wid, rg, col, lane);          // r h1 -> w h0
    __syncthreads();                                         // h0 ready
    layer2_red(W2, g4_b, h0, pacc, wid, rg, col, lane);      // r h0
    stage_h(h1, Ab, Bb1, tid);                               // w h1 (overlaps)
    __syncthreads();                                         // h1 ready

    // ---- pp1 (buffers flipped) ----
    layer_sw(W0, g2_b, h1, h0, wid, rg, col, lane);
    __syncthreads();
    layer_sw(W1, g3_b, h0, h1, wid, rg, col, lane);
    __syncthreads();
    layer2_red(W2, g4_b, h1, pacc, wid, rg, col, lane);

    if (rg == 0) {
        #pragma unroll
        for (int nf = 0; nf < 4; ++nf)
            partial[(size_t)(b * NTILE + t) * HID + wid * 64 + nf * 16 + col]
                = pacc[nf];
    }
}

// ---------------------------------------------------------------------------
// Kernel 3: per-batch reduce over tiles + f-network (fp32) + log_softmax
// ---------------------------------------------------------------------------
__global__ __launch_bounds__(256) void fuse_kernel(
        const float* __restrict__ partial,
        const float* __restrict__ f1_w, const float* __restrict__ f1_b,
        const float* __restrict__ f2_w, const float* __restrict__ f2_b,
        const float* __restrict__ f3_w, const float* __restrict__ f3_b,
        float* __restrict__ out) {
    int b = blockIdx.x;
    int tid = threadIdx.x;
    __shared__ float xg[HID];
    __shared__ float h1[HID];
    __shared__ float h2v[HID];
    __shared__ float lred[NOUT];
    __shared__ float lse;

    float s = 0.f;
    for (int t = 0; t < NTILE; ++t)
        s += partial[(size_t)(b * NTILE + t) * HID + tid];
    xg[tid] = s;
    __syncthreads();

    float a1 = f1_b[tid];
    for (int k = 0; k < HID; ++k)
        a1 += xg[k] * f1_w[k * HID + tid];
    h1[tid] = a1 > 0.f ? a1 : 0.f;
    __syncthreads();

    float a2 = f2_b[tid];
    for (int k = 0; k < HID; ++k)
        a2 += h1[k] * f2_w[k * HID + tid];
    h2v[tid] = a2 > 0.f ? a2 : 0.f;
    __syncthreads();

    float logit = 0.f;
    if (tid < NOUT) {
        logit = f3_b[tid];
        for (int k = 0; k < HID; ++k)
            logit += h2v[k] * f3_w[k * NOUT + tid];
        lred[tid] = logit;
    }
    __syncthreads();
    if (tid == 0) {
        float mx = lred[0];
        for (int j = 1; j < NOUT; ++j) mx = fmaxf(mx, lred[j]);
        float se = 0.f;
        for (int j = 0; j < NOUT; ++j) se += expf(lred[j] - mx);
        lse = mx + logf(se);
    }
    __syncthreads();
    if (tid < NOUT)
        out[b * NOUT + tid] = logit - lse;
}

// ---------------------------------------------------------------------------
extern "C" void kernel_launch(void* const* d_in, const int* in_sizes, int n_in,
                              void* d_out, int out_size, void* d_ws, size_t ws_size,
                              hipStream_t stream) {
    const float* x    = (const float*)d_in[0];
    const float* qst  = (const float*)d_in[1];
    const float* g1_w = (const float*)d_in[2];
    const float* g1_b = (const float*)d_in[3];
    const float* g2_w = (const float*)d_in[4];
    const float* g2_b = (const float*)d_in[5];
    const float* g3_w = (const float*)d_in[6];
    const float* g3_b = (const float*)d_in[7];
    const float* g4_w = (const float*)d_in[8];
    const float* g4_b = (const float*)d_in[9];
    const float* f1_w = (const float*)d_in[10];
    const float* f1_b = (const float*)d_in[11];
    const float* f2_w = (const float*)d_in[12];
    const float* f2_b = (const float*)d_in[13];
    const float* f3_w = (const float*)d_in[14];
    const float* f3_b = (const float*)d_in[15];
    float* out = (float*)d_out;

    char* ws = (char*)d_ws;
    _Float16* Abf = (_Float16*)ws;                          // 2 MiB
    _Float16* Bbf = (_Float16*)(ws + (2u << 20));           // 2 MiB
    _Float16* Wt  = (_Float16*)(ws + (4u << 20));           // 384 KiB
    float* partial = (float*)(ws + (4u << 20) + (512u << 10));   // 2 MiB

    prep_all<<<384 + NB, 256, 0, stream>>>(x, qst, g1_w, g1_b, g2_w, g3_w, g4_w,
                                           Abf, Bbf, Wt);
    rn_main<<<NB * NTILE, 256, 0, stream>>>(Abf, Bbf, Wt, g2_b, g3_b, g4_b, partial);
    fuse_kernel<<<NB, 256, 0, stream>>>(partial, f1_w, f1_b, f2_w, f2_b, f3_w, f3_b, out);
}

// Round 19
// 129.611 us; speedup vs baseline: 4.0292x; 1.2332x over previous
//
#include <hip/hip_runtime.h>
#include <hip/hip_bf16.h>
#include <math.h>

#define NB   64      // batch
#define D2   64      // objects per batch
#define OBJ  26      // K+2 features per object
#define NQST 11
#define HID  256
#define NOUT 28
#define NTILE 32     // p-tiles per batch (2 p's each, processed sequentially)
#define HSTRE 264    // h row stride in fp16 ELEMENTS (528 B = 512 data + 16 pad)
                     // row base mod 128B = 16*m -> 8 slots x 16B cover all 32
                     // banks, 2 lanes/slot = free (m136); AND ks-affine:
                     // ds_read offset:ks*64 immediates, zero per-ks addr VALU
                     // (the XOR swizzle collided with ks bit 6 -> per-ks
                     // recompute, ~400 VALU/thread).

typedef _Float16 f16x8 __attribute__((ext_vector_type(8)));
typedef __attribute__((ext_vector_type(4))) float f32x4;
typedef __attribute__((ext_vector_type(2))) unsigned int u32x2;

__device__ __forceinline__ unsigned pack_h2(float a, float b) {
    auto r = __builtin_amdgcn_cvt_pkrtz(a, b);   // v_cvt_pkrtz_f16_f32
    union U { decltype(r) h; unsigned u; } v;
    v.h = r;
    return v.u;
}
__device__ __forceinline__ f16x8 relu8(f16x8 x) {
    f16x8 z = {0, 0, 0, 0, 0, 0, 0, 0};
#if __has_builtin(__builtin_elementwise_max)
    return __builtin_elementwise_max(x, z);    // v_pk_max_f16 x4
#else
    #pragma unroll
    for (int j = 0; j < 8; ++j) x[j] = x[j] > (_Float16)0 ? x[j] : (_Float16)0;
    return x;
#endif
}

// ---------------------------------------------------------------------------
// Kernel 1 (merged):
// blocks 0..383: FRAG-MAJOR weight repack (fp16). Block = ((l*16+nb)*8+ks);
//   element e = lane*8+j holds W_l[k][n], n = nb*16+(lane&15),
//   k = ks*32+(lane>>4)*8+j. Main-kernel W-frag load = ONE contiguous 1 KB
//   burst at base + ks*1024B.
// blocks 384..447: per-batch A/B (fp16) from the g1 decomposition:
//   A[q] = o[q] @ g1_w[0:26]
//   B[p] = o[p] @ g1_w[26:52] + qst @ g1_w[52:63] + g1_b
// ---------------------------------------------------------------------------
__global__ __launch_bounds__(256) void prep_all(
        const float* __restrict__ x, const float* __restrict__ qst,
        const float* __restrict__ g1_w, const float* __restrict__ g1_b,
        const float* __restrict__ g2_w, const float* __restrict__ g3_w,
        const float* __restrict__ g4_w,
        _Float16* __restrict__ Abf, _Float16* __restrict__ Bbf,
        _Float16* __restrict__ Wt) {
    if (blockIdx.x < 384) {
        int blk = blockIdx.x;
        int ks = blk & 7;
        int nbl = blk >> 3;      // l*16+nb
        int l = nbl >> 4;
        int nb = nbl & 15;
        const float* W = (l == 0) ? g2_w : ((l == 1) ? g3_w : g4_w);
        int t = threadIdx.x;
        #pragma unroll
        for (int u = 0; u < 2; ++u) {
            int e = t + u * 256;             // 0..511
            int lane = e >> 3;
            int j = e & 7;
            int n = nb * 16 + (lane & 15);
            int k = ks * 32 + (lane >> 4) * 8 + j;
            Wt[blk * 512 + e] = (_Float16)W[k * HID + n];
        }
        return;
    }
    int b = blockIdx.x - 384;
    int tid = threadIdx.x;
    __shared__ float o_lds[D2][OBJ];
    for (int idx = tid; idx < 24 * D2; idx += 256) {
        int c = idx >> 6, pos = idx & 63;
        o_lds[pos][c] = x[(b * 24 + c) * D2 + pos];
    }
    if (tid < D2) {
        o_lds[tid][24] = (float)(tid & 7) * (8.0f / 7.0f) - 4.0f;  // cx
        o_lds[tid][25] = (float)(tid >> 3) * (8.0f / 7.0f) - 4.0f; // cy
    }
    __syncthreads();
    int n = tid;  // 0..255
    float qpart = g1_b[n];
    for (int s = 0; s < NQST; ++s)
        qpart += qst[b * NQST + s] * g1_w[(2 * OBJ + s) * HID + n];
    for (int q0 = 0; q0 < D2; q0 += 16) {
        float accA[16], accB[16];
        #pragma unroll
        for (int i = 0; i < 16; ++i) { accA[i] = 0.f; accB[i] = 0.f; }
        for (int c = 0; c < OBJ; ++c) {
            float wA = g1_w[c * HID + n];
            float wB = g1_w[(OBJ + c) * HID + n];
            #pragma unroll
            for (int i = 0; i < 16; ++i) {
                float ov = o_lds[q0 + i][c];
                accA[i] += ov * wA;
                accB[i] += ov * wB;
            }
        }
        #pragma unroll
        for (int i = 0; i < 16; ++i) {
            int q = q0 + i;
            Abf[(b * D2 + q) * HID + n] = (_Float16)accA[i];
            Bbf[(b * D2 + q) * HID + n] = (_Float16)(accB[i] + qpart);
        }
    }
}

// ---------------------------------------------------------------------------
// rn_main helpers. 256 threads = 4 waves, per-wave n-slice 64.
// h LDS layout: row m at element m*HSTRE, k element K at index K in row.
// ---------------------------------------------------------------------------

// stage h[m][k] = relu(A[m][k] + B[k]) into hbuf.
__device__ __forceinline__ void stage_h(
        _Float16* hbuf, const _Float16* __restrict__ Ab,
        const _Float16* __restrict__ Bb, int tid) {
    #pragma unroll 2
    for (int i = 0; i < 8; ++i) {
        int c = tid + i * 256;       // 2048 chunks of 8 fp16
        int m = c >> 5;              // 0..63
        int k0 = (c & 31) * 8;
        f16x8 av = *(const f16x8*)(Ab + m * HID + k0);
        f16x8 bv = *(const f16x8*)(Bb + k0);
        f16x8 hv = relu8(av + bv);   // 4x pk_add + 4x pk_max
        *(f16x8*)(hbuf + m * HSTRE + k0) = hv;
    }
}

// layers 0/1: swapped-operand mfma(W,h) -> D[n][m]; bias-in-acc; epilogue
// relu+pack -> OTHER buffer. W: frag-major bursts, ks-granularity ping-pong
// (wbuf[2][4] = 32 regs in flight). setprio(1) around MFMA cluster.
// hfr reads: per-mf base pointer + ks*32-element immediate offsets.
__device__ __forceinline__ void layer_sw(
        const _Float16* __restrict__ Wl, const float* __restrict__ bias,
        const _Float16* hin, _Float16* hout,
        int wid, int rg, int col, int lane) {
    const _Float16* wb0 = Wl + (size_t)(wid * 4 + 0) * 4096 + lane * 8;
    const _Float16* wb1 = Wl + (size_t)(wid * 4 + 1) * 4096 + lane * 8;
    const _Float16* wb2 = Wl + (size_t)(wid * 4 + 2) * 4096 + lane * 8;
    const _Float16* wb3 = Wl + (size_t)(wid * 4 + 3) * 4096 + lane * 8;

    f32x4 acc[4][4];   // [nf][mf]
    #pragma unroll
    for (int nf = 0; nf < 4; ++nf) {
        f32x4 b4 = *(const f32x4*)(bias + wid * 64 + nf * 16 + rg * 4);
        #pragma unroll
        for (int mf = 0; mf < 4; ++mf)
            acc[nf][mf] = b4;               // bias-in-acc
    }

    // per-mf fragment bases (affine; ks -> offset immediate)
    const _Float16* hr0 = hin + (0 * 16 + col) * HSTRE + rg * 8;
    const _Float16* hr1 = hin + (1 * 16 + col) * HSTRE + rg * 8;
    const _Float16* hr2 = hin + (2 * 16 + col) * HSTRE + rg * 8;
    const _Float16* hr3 = hin + (3 * 16 + col) * HSTRE + rg * 8;

    f16x8 wbuf[2][4];   // ks ping-pong: 32 regs in flight
    wbuf[0][0] = *(const f16x8*)(wb0);
    wbuf[0][1] = *(const f16x8*)(wb1);
    wbuf[0][2] = *(const f16x8*)(wb2);
    wbuf[0][3] = *(const f16x8*)(wb3);

    #pragma unroll
    for (int ks = 0; ks < 8; ++ks) {
        const int cur = ks & 1;
        if (ks < 7) {
            int off = (ks + 1) * 512;
            wbuf[cur ^ 1][0] = *(const f16x8*)(wb0 + off);
            wbuf[cur ^ 1][1] = *(const f16x8*)(wb1 + off);
            wbuf[cur ^ 1][2] = *(const f16x8*)(wb2 + off);
            wbuf[cur ^ 1][3] = *(const f16x8*)(wb3 + off);
        }
        f16x8 hfr[4];
        hfr[0] = *(const f16x8*)(hr0 + ks * 32);
        hfr[1] = *(const f16x8*)(hr1 + ks * 32);
        hfr[2] = *(const f16x8*)(hr2 + ks * 32);
        hfr[3] = *(const f16x8*)(hr3 + ks * 32);
        __builtin_amdgcn_s_setprio(1);
        #pragma unroll
        for (int nf = 0; nf < 4; ++nf)
            #pragma unroll
            for (int mf = 0; mf < 4; ++mf)
                acc[nf][mf] = __builtin_amdgcn_mfma_f32_16x16x32_f16(
                    wbuf[cur][nf], hfr[mf], acc[nf][mf], 0, 0, 0);
        __builtin_amdgcn_s_setprio(0);
    }
    // epilogue: n = wid*64+nf*16+rg*4+r, m = mf*16+col -> hout
    #pragma unroll
    for (int nf = 0; nf < 4; ++nf) {
        int n0 = wid * 64 + nf * 16 + rg * 4;
        #pragma unroll
        for (int mf = 0; mf < 4; ++mf) {
            int m = mf * 16 + col;
            u32x2 w;
            w[0] = pack_h2(fmaxf(acc[nf][mf][0], 0.f), fmaxf(acc[nf][mf][1], 0.f));
            w[1] = pack_h2(fmaxf(acc[nf][mf][2], 0.f), fmaxf(acc[nf][mf][3], 0.f));
            *(u32x2*)(hout + m * HSTRE + n0) = w;
        }
    }
}

// layer 2: unswapped mfma(h,W) -> D[m][n]; bias-in-acc; relu + pair-sum.
// Same frag-major ks ping-pong + setprio.
__device__ __forceinline__ void layer2_red(
        const _Float16* __restrict__ Wl, const float* __restrict__ bias,
        const _Float16* hin, float* pacc, int wid, int rg, int col, int lane) {
    const _Float16* wb0 = Wl + (size_t)(wid * 4 + 0) * 4096 + lane * 8;
    const _Float16* wb1 = Wl + (size_t)(wid * 4 + 1) * 4096 + lane * 8;
    const _Float16* wb2 = Wl + (size_t)(wid * 4 + 2) * 4096 + lane * 8;
    const _Float16* wb3 = Wl + (size_t)(wid * 4 + 3) * 4096 + lane * 8;

    f32x4 acc[4][4];   // [mf][nf]
    #pragma unroll
    for (int nf = 0; nf < 4; ++nf) {
        float bv = bias[wid * 64 + nf * 16 + col];
        f32x4 bb = (f32x4){bv, bv, bv, bv};
        #pragma unroll
        for (int mf = 0; mf < 4; ++mf)
            acc[mf][nf] = bb;
    }

    const _Float16* hr0 = hin + (0 * 16 + col) * HSTRE + rg * 8;
    const _Float16* hr1 = hin + (1 * 16 + col) * HSTRE + rg * 8;
    const _Float16* hr2 = hin + (2 * 16 + col) * HSTRE + rg * 8;
    const _Float16* hr3 = hin + (3 * 16 + col) * HSTRE + rg * 8;

    f16x8 wbuf[2][4];
    wbuf[0][0] = *(const f16x8*)(wb0);
    wbuf[0][1] = *(const f16x8*)(wb1);
    wbuf[0][2] = *(const f16x8*)(wb2);
    wbuf[0][3] = *(const f16x8*)(wb3);

    #pragma unroll
    for (int ks = 0; ks < 8; ++ks) {
        const int cur = ks & 1;
        if (ks < 7) {
            int off = (ks + 1) * 512;
            wbuf[cur ^ 1][0] = *(const f16x8*)(wb0 + off);
            wbuf[cur ^ 1][1] = *(const f16x8*)(wb1 + off);
            wbuf[cur ^ 1][2] = *(const f16x8*)(wb2 + off);
            wbuf[cur ^ 1][3] = *(const f16x8*)(wb3 + off);
        }
        f16x8 hfr[4];
        hfr[0] = *(const f16x8*)(hr0 + ks * 32);
        hfr[1] = *(const f16x8*)(hr1 + ks * 32);
        hfr[2] = *(const f16x8*)(hr2 + ks * 32);
        hfr[3] = *(const f16x8*)(hr3 + ks * 32);
        __builtin_amdgcn_s_setprio(1);
        #pragma unroll
        for (int mf = 0; mf < 4; ++mf)
            #pragma unroll
            for (int nf = 0; nf < 4; ++nf)
                acc[mf][nf] = __builtin_amdgcn_mfma_f32_16x16x32_f16(
                    hfr[mf], wbuf[cur][nf], acc[mf][nf], 0, 0, 0);
        __builtin_amdgcn_s_setprio(0);
    }
    #pragma unroll
    for (int nf = 0; nf < 4; ++nf) {
        float s = 0.f;
        #pragma unroll
        for (int mf = 0; mf < 4; ++mf)
            #pragma unroll
            for (int r = 0; r < 4; ++r)
                s += fmaxf(acc[mf][nf][r], 0.f);
        s += __shfl_xor(s, 16);
        s += __shfl_xor(s, 32);
        pacc[nf] += s;
    }
}

// ---------------------------------------------------------------------------
// Kernel 2: main fused g-network — r18 champion + padded-stride h (no XOR).
// 256 threads = 4 waves, wave n-slice 64, double-buffered h (2x33 KiB),
// 6 barriers per WG, launch_bounds(256,2): 2 blocks/CU. fp16 datapath,
// frag-major W bursts, ks ping-pong, setprio. Static buffers, unrolled
// pp0/pp1 (r15's loop-carried pointer swap caused a scratch explosion).
// ---------------------------------------------------------------------------
__global__ __launch_bounds__(256, 2) void rn_main(
        const _Float16* __restrict__ Abf, const _Float16* __restrict__ Bbf,
        const _Float16* __restrict__ Wt,
        const float* __restrict__ g2_b, const float* __restrict__ g3_b,
        const float* __restrict__ g4_b, float* __restrict__ partial) {
    // XCD-aware swizzle: 2048 WGs, 8 XCDs (2048 % 8 == 0 -> bijective)
    int wg = blockIdx.x;
    int swz = (wg & 7) * 256 + (wg >> 3);
    int b = swz >> 5;
    int t = swz & 31;

    __shared__ _Float16 h0[D2 * HSTRE];   // 33 KiB
    __shared__ _Float16 h1[D2 * HSTRE];   // 33 KiB

    int tid = threadIdx.x;   // 0..255
    int lane = tid & 63;
    int wid = tid >> 6;      // wave 0..3 -> n-slice of 64
    int rg = lane >> 4;      // 0..3
    int col = lane & 15;

    const _Float16* Ab  = Abf + (size_t)(b * D2) * HID;
    const _Float16* Bb0 = Bbf + (size_t)(b * D2 + t * 2 + 0) * HID;
    const _Float16* Bb1 = Bbf + (size_t)(b * D2 + t * 2 + 1) * HID;
    const _Float16* W0 = Wt;                        // 65536 elems/layer
    const _Float16* W1 = Wt + (size_t)1 * 65536;
    const _Float16* W2 = Wt + (size_t)2 * 65536;

    float pacc[4] = {0.f, 0.f, 0.f, 0.f};

    // ---- pp0 ----
    stage_h(h0, Ab, Bb0, tid);
    __syncthreads();                                         // h0 ready
    layer_sw(W0, g2_b, h0, h1, wid, rg, col, lane);          // r h0 -> w h1
    __syncthreads();                                         // h1 ready
    layer_sw(W1, g3_b, h1, h0, wid, rg, col, lane);          // r h1 -> w h0
    __syncthreads();                                         // h0 ready
    layer2_red(W2, g4_b, h0, pacc, wid, rg, col, lane);      // r h0
    stage_h(h1, Ab, Bb1, tid);                               // w h1 (overlaps)
    __syncthreads();                                         // h1 ready

    // ---- pp1 (buffers flipped) ----
    layer_sw(W0, g2_b, h1, h0, wid, rg, col, lane);
    __syncthreads();
    layer_sw(W1, g3_b, h0, h1, wid, rg, col, lane);
    __syncthreads();
    layer2_red(W2, g4_b, h1, pacc, wid, rg, col, lane);

    if (rg == 0) {
        #pragma unroll
        for (int nf = 0; nf < 4; ++nf)
            partial[(size_t)(b * NTILE + t) * HID + wid * 64 + nf * 16 + col]
                = pacc[nf];
    }
}

// ---------------------------------------------------------------------------
// Kernel 3: per-batch reduce over tiles + f-network (fp32) + log_softmax
// ---------------------------------------------------------------------------
__global__ __launch_bounds__(256) void fuse_kernel(
        const float* __restrict__ partial,
        const float* __restrict__ f1_w, const float* __restrict__ f1_b,
        const float* __restrict__ f2_w, const float* __restrict__ f2_b,
        const float* __restrict__ f3_w, const float* __restrict__ f3_b,
        float* __restrict__ out) {
    int b = blockIdx.x;
    int tid = threadIdx.x;
    __shared__ float xg[HID];
    __shared__ float h1[HID];
    __shared__ float h2v[HID];
    __shared__ float lred[NOUT];
    __shared__ float lse;

    float s = 0.f;
    for (int t = 0; t < NTILE; ++t)
        s += partial[(size_t)(b * NTILE + t) * HID + tid];
    xg[tid] = s;
    __syncthreads();

    float a1 = f1_b[tid];
    for (int k = 0; k < HID; ++k)
        a1 += xg[k] * f1_w[k * HID + tid];
    h1[tid] = a1 > 0.f ? a1 : 0.f;
    __syncthreads();

    float a2 = f2_b[tid];
    for (int k = 0; k < HID; ++k)
        a2 += h1[k] * f2_w[k * HID + tid];
    h2v[tid] = a2 > 0.f ? a2 : 0.f;
    __syncthreads();

    float logit = 0.f;
    if (tid < NOUT) {
        logit = f3_b[tid];
        for (int k = 0; k < HID; ++k)
            logit += h2v[k] * f3_w[k * NOUT + tid];
        lred[tid] = logit;
    }
    __syncthreads();
    if (tid == 0) {
        float mx = lred[0];
        for (int j = 1; j < NOUT; ++j) mx = fmaxf(mx, lred[j]);
        float se = 0.f;
        for (int j = 0; j < NOUT; ++j) se += expf(lred[j] - mx);
        lse = mx + logf(se);
    }
    __syncthreads();
    if (tid < NOUT)
        out[b * NOUT + tid] = logit - lse;
}

// ---------------------------------------------------------------------------
extern "C" void kernel_launch(void* const* d_in, const int* in_sizes, int n_in,
                              void* d_out, int out_size, void* d_ws, size_t ws_size,
                              hipStream_t stream) {
    const float* x    = (const float*)d_in[0];
    const float* qst  = (const float*)d_in[1];
    const float* g1_w = (const float*)d_in[2];
    const float* g1_b = (const float*)d_in[3];
    const float* g2_w = (const float*)d_in[4];
    const float* g2_b = (const float*)d_in[5];
    const float* g3_w = (const float*)d_in[6];
    const float* g3_b = (const float*)d_in[7];
    const float* g4_w = (const float*)d_in[8];
    const float* g4_b = (const float*)d_in[9];
    const float* f1_w = (const float*)d_in[10];
    const float* f1_b = (const float*)d_in[11];
    const float* f2_w = (const float*)d_in[12];
    const float* f2_b = (const float*)d_in[13];
    const float* f3_w = (const float*)d_in[14];
    const float* f3_b = (const float*)d_in[15];
    float* out = (float*)d_out;

    char* ws = (char*)d_ws;
    _Float16* Abf = (_Float16*)ws;                          // 2 MiB
    _Float16* Bbf = (_Float16*)(ws + (2u << 20));           // 2 MiB
    _Float16* Wt  = (_Float16*)(ws + (4u << 20));           // 384 KiB
    float* partial = (float*)(ws + (4u << 20) + (512u << 10));   // 2 MiB

    prep_all<<<384 + NB, 256, 0, stream>>>(x, qst, g1_w, g1_b, g2_w, g3_w, g4_w,
                                           Abf, Bbf, Wt);
    rn_main<<<NB * NTILE, 256, 0, stream>>>(Abf, Bbf, Wt, g2_b, g3_b, g4_b, partial);
    fuse_kernel<<<NB, 256, 0, stream>>>(partial, f1_w, f1_b, f2_w, f2_b, f3_w, f3_b, out);
}

// Round 20
// 118.561 us; speedup vs baseline: 4.4047x; 1.0932x over previous
//
#include <hip/hip_runtime.h>
#include <hip/hip_bf16.h>
#include <math.h>

#define NB   64      // batch
#define D2   64      // objects per batch
#define OBJ  26      // K+2 features per object
#define NQST 11
#define HID  256
#define NOUT 28
#define NTILE 32     // p-tiles per batch (2 p's each, processed sequentially)
#define HSTRE 264    // h row stride in fp16 ELEMENTS (528 B): 2-way-free banks
                     // AND ks-affine addresses (ds offset immediates)

typedef _Float16 f16x8 __attribute__((ext_vector_type(8)));
typedef _Float16 f16x4 __attribute__((ext_vector_type(4)));
typedef __attribute__((ext_vector_type(4))) float f32x4;
typedef __attribute__((ext_vector_type(2))) unsigned int u32x2;

__device__ __forceinline__ unsigned pack_h2(float a, float b) {
    auto r = __builtin_amdgcn_cvt_pkrtz(a, b);   // v_cvt_pkrtz_f16_f32
    union U { decltype(r) h; unsigned u; } v;
    v.h = r;
    return v.u;
}
__device__ __forceinline__ f16x8 relu8(f16x8 x) {
    f16x8 z = {0, 0, 0, 0, 0, 0, 0, 0};
#if __has_builtin(__builtin_elementwise_max)
    return __builtin_elementwise_max(x, z);    // v_pk_max_f16 x4
#else
    #pragma unroll
    for (int j = 0; j < 8; ++j) x[j] = x[j] > (_Float16)0 ? x[j] : (_Float16)0;
    return x;
#endif
}
// pack 4 f32 -> 4 fp16 (rtz) then relu in packed fp16: 2 cvt_pk + 2 pk_max
__device__ __forceinline__ u32x2 pack_relu4(float a0, float a1, float a2, float a3) {
    u32x2 w;
    w[0] = pack_h2(a0, a1);
    w[1] = pack_h2(a2, a3);
#if __has_builtin(__builtin_elementwise_max)
    union { u32x2 u; f16x4 h; } v;
    v.u = w;
    f16x4 z = {0, 0, 0, 0};
    v.h = __builtin_elementwise_max(v.h, z);
    return v.u;
#else
    union { u32x2 u; f16x4 h; } v; v.u = w;
    #pragma unroll
    for (int j = 0; j < 4; ++j) v.h[j] = v.h[j] > (_Float16)0 ? v.h[j] : (_Float16)0;
    return v.u;
#endif
}

// ---------------------------------------------------------------------------
// Kernel 1 (merged):
// blocks 0..383: FRAG-MAJOR weight repack (fp16). Block = ((l*16+nb)*8+ks);
//   element e = lane*8+j holds W_l[k][n], n = nb*16+(lane&15),
//   k = ks*32+(lane>>4)*8+j. Main-kernel W-frag load = ONE contiguous 1 KB
//   burst at base + ks*1024B.
// blocks 384..639: per-batch A/B (fp16), 4 blocks per batch (16 q-rows each):
//   A[q] = o[q] @ g1_w[0:26]
//   B[p] = o[p] @ g1_w[26:52] + qst @ g1_w[52:63] + g1_b
// ---------------------------------------------------------------------------
__global__ __launch_bounds__(256) void prep_all(
        const float* __restrict__ x, const float* __restrict__ qst,
        const float* __restrict__ g1_w, const float* __restrict__ g1_b,
        const float* __restrict__ g2_w, const float* __restrict__ g3_w,
        const float* __restrict__ g4_w,
        _Float16* __restrict__ Abf, _Float16* __restrict__ Bbf,
        _Float16* __restrict__ Wt) {
    if (blockIdx.x < 384) {
        int blk = blockIdx.x;
        int ks = blk & 7;
        int nbl = blk >> 3;      // l*16+nb
        int l = nbl >> 4;
        int nb = nbl & 15;
        const float* W = (l == 0) ? g2_w : ((l == 1) ? g3_w : g4_w);
        int t = threadIdx.x;
        #pragma unroll
        for (int u = 0; u < 2; ++u) {
            int e = t + u * 256;             // 0..511
            int lane = e >> 3;
            int j = e & 7;
            int n = nb * 16 + (lane & 15);
            int k = ks * 32 + (lane >> 4) * 8 + j;
            Wt[blk * 512 + e] = (_Float16)W[k * HID + n];
        }
        return;
    }
    int blk = blockIdx.x - 384;
    int b = blk >> 2;            // batch
    int q0 = (blk & 3) * 16;     // 16 q-rows per block
    int tid = threadIdx.x;
    __shared__ float o_lds[16][OBJ];
    for (int idx = tid; idx < 24 * 16; idx += 256) {
        int c = idx >> 4, i = idx & 15;
        o_lds[i][c] = x[(b * 24 + c) * D2 + q0 + i];
    }
    if (tid < 16) {
        int q = q0 + tid;
        o_lds[tid][24] = (float)(q & 7) * (8.0f / 7.0f) - 4.0f;  // cx
        o_lds[tid][25] = (float)(q >> 3) * (8.0f / 7.0f) - 4.0f; // cy
    }
    __syncthreads();
    int n = tid;  // 0..255
    float qpart = g1_b[n];
    for (int s = 0; s < NQST; ++s)
        qpart += qst[b * NQST + s] * g1_w[(2 * OBJ + s) * HID + n];
    float accA[16], accB[16];
    #pragma unroll
    for (int i = 0; i < 16; ++i) { accA[i] = 0.f; accB[i] = 0.f; }
    for (int c = 0; c < OBJ; ++c) {
        float wA = g1_w[c * HID + n];
        float wB = g1_w[(OBJ + c) * HID + n];
        #pragma unroll
        for (int i = 0; i < 16; ++i) {
            float ov = o_lds[i][c];
            accA[i] += ov * wA;
            accB[i] += ov * wB;
        }
    }
    #pragma unroll
    for (int i = 0; i < 16; ++i) {
        int q = q0 + i;
        Abf[(b * D2 + q) * HID + n] = (_Float16)accA[i];
        Bbf[(b * D2 + q) * HID + n] = (_Float16)(accB[i] + qpart);
    }
}

// ---------------------------------------------------------------------------
// rn_main helpers. 256 threads = 4 waves, per-wave n-slice 64.
// h LDS layout: row m at element m*HSTRE, k element K at index K in row.
// ---------------------------------------------------------------------------

// stage h[m][k] = relu(A[m][k] + B[k]) into hbuf.
__device__ __forceinline__ void stage_h(
        _Float16* hbuf, const _Float16* __restrict__ Ab,
        const _Float16* __restrict__ Bb, int tid) {
    #pragma unroll 2
    for (int i = 0; i < 8; ++i) {
        int c = tid + i * 256;       // 2048 chunks of 8 fp16
        int m = c >> 5;              // 0..63
        int k0 = (c & 31) * 8;
        f16x8 av = *(const f16x8*)(Ab + m * HID + k0);
        f16x8 bv = *(const f16x8*)(Bb + k0);
        f16x8 hv = relu8(av + bv);   // 4x pk_add + 4x pk_max
        *(f16x8*)(hbuf + m * HSTRE + k0) = hv;
    }
}

// layers 0/1: swapped-operand mfma(W,h) -> D[n][m]; bias-in-acc; epilogue
// pack-then-relu (2 cvt_pk + 2 pk_max per frag) -> OTHER buffer.
// W: frag-major bursts, ks ping-pong (wbuf[2][4]). setprio around MFMAs.
__device__ __forceinline__ void layer_sw(
        const _Float16* __restrict__ Wl, const float* __restrict__ bias,
        const _Float16* hin, _Float16* hout,
        int wid, int rg, int col, int lane) {
    const _Float16* wb0 = Wl + (size_t)(wid * 4 + 0) * 4096 + lane * 8;
    const _Float16* wb1 = Wl + (size_t)(wid * 4 + 1) * 4096 + lane * 8;
    const _Float16* wb2 = Wl + (size_t)(wid * 4 + 2) * 4096 + lane * 8;
    const _Float16* wb3 = Wl + (size_t)(wid * 4 + 3) * 4096 + lane * 8;

    f32x4 acc[4][4];   // [nf][mf]
    #pragma unroll
    for (int nf = 0; nf < 4; ++nf) {
        f32x4 b4 = *(const f32x4*)(bias + wid * 64 + nf * 16 + rg * 4);
        #pragma unroll
        for (int mf = 0; mf < 4; ++mf)
            acc[nf][mf] = b4;               // bias-in-acc
    }

    const _Float16* hr0 = hin + (0 * 16 + col) * HSTRE + rg * 8;
    const _Float16* hr1 = hin + (1 * 16 + col) * HSTRE + rg * 8;
    const _Float16* hr2 = hin + (2 * 16 + col) * HSTRE + rg * 8;
    const _Float16* hr3 = hin + (3 * 16 + col) * HSTRE + rg * 8;

    f16x8 wbuf[2][4];   // ks ping-pong: 32 regs in flight
    wbuf[0][0] = *(const f16x8*)(wb0);
    wbuf[0][1] = *(const f16x8*)(wb1);
    wbuf[0][2] = *(const f16x8*)(wb2);
    wbuf[0][3] = *(const f16x8*)(wb3);

    #pragma unroll
    for (int ks = 0; ks < 8; ++ks) {
        const int cur = ks & 1;
        if (ks < 7) {
            int off = (ks + 1) * 512;
            wbuf[cur ^ 1][0] = *(const f16x8*)(wb0 + off);
            wbuf[cur ^ 1][1] = *(const f16x8*)(wb1 + off);
            wbuf[cur ^ 1][2] = *(const f16x8*)(wb2 + off);
            wbuf[cur ^ 1][3] = *(const f16x8*)(wb3 + off);
        }
        f16x8 hfr[4];
        hfr[0] = *(const f16x8*)(hr0 + ks * 32);
        hfr[1] = *(const f16x8*)(hr1 + ks * 32);
        hfr[2] = *(const f16x8*)(hr2 + ks * 32);
        hfr[3] = *(const f16x8*)(hr3 + ks * 32);
        __builtin_amdgcn_s_setprio(1);
        #pragma unroll
        for (int nf = 0; nf < 4; ++nf)
            #pragma unroll
            for (int mf = 0; mf < 4; ++mf)
                acc[nf][mf] = __builtin_amdgcn_mfma_f32_16x16x32_f16(
                    wbuf[cur][nf], hfr[mf], acc[nf][mf], 0, 0, 0);
        __builtin_amdgcn_s_setprio(0);
    }
    // epilogue: n = wid*64+nf*16+rg*4+r, m = mf*16+col -> hout
    #pragma unroll
    for (int nf = 0; nf < 4; ++nf) {
        int n0 = wid * 64 + nf * 16 + rg * 4;
        #pragma unroll
        for (int mf = 0; mf < 4; ++mf) {
            int m = mf * 16 + col;
            u32x2 w = pack_relu4(acc[nf][mf][0], acc[nf][mf][1],
                                 acc[nf][mf][2], acc[nf][mf][3]);
            *(u32x2*)(hout + m * HSTRE + n0) = w;
        }
    }
}

// layer 2: unswapped mfma(h,W) -> D[m][n]; bias-in-acc; relu + pair-sum.
// Same frag-major ks ping-pong + setprio.
__device__ __forceinline__ void layer2_red(
        const _Float16* __restrict__ Wl, const float* __restrict__ bias,
        const _Float16* hin, float* pacc, int wid, int rg, int col, int lane) {
    const _Float16* wb0 = Wl + (size_t)(wid * 4 + 0) * 4096 + lane * 8;
    const _Float16* wb1 = Wl + (size_t)(wid * 4 + 1) * 4096 + lane * 8;
    const _Float16* wb2 = Wl + (size_t)(wid * 4 + 2) * 4096 + lane * 8;
    const _Float16* wb3 = Wl + (size_t)(wid * 4 + 3) * 4096 + lane * 8;

    f32x4 acc[4][4];   // [mf][nf]
    #pragma unroll
    for (int nf = 0; nf < 4; ++nf) {
        float bv = bias[wid * 64 + nf * 16 + col];
        f32x4 bb = (f32x4){bv, bv, bv, bv};
        #pragma unroll
        for (int mf = 0; mf < 4; ++mf)
            acc[mf][nf] = bb;
    }

    const _Float16* hr0 = hin + (0 * 16 + col) * HSTRE + rg * 8;
    const _Float16* hr1 = hin + (1 * 16 + col) * HSTRE + rg * 8;
    const _Float16* hr2 = hin + (2 * 16 + col) * HSTRE + rg * 8;
    const _Float16* hr3 = hin + (3 * 16 + col) * HSTRE + rg * 8;

    f16x8 wbuf[2][4];
    wbuf[0][0] = *(const f16x8*)(wb0);
    wbuf[0][1] = *(const f16x8*)(wb1);
    wbuf[0][2] = *(const f16x8*)(wb2);
    wbuf[0][3] = *(const f16x8*)(wb3);

    #pragma unroll
    for (int ks = 0; ks < 8; ++ks) {
        const int cur = ks & 1;
        if (ks < 7) {
            int off = (ks + 1) * 512;
            wbuf[cur ^ 1][0] = *(const f16x8*)(wb0 + off);
            wbuf[cur ^ 1][1] = *(const f16x8*)(wb1 + off);
            wbuf[cur ^ 1][2] = *(const f16x8*)(wb2 + off);
            wbuf[cur ^ 1][3] = *(const f16x8*)(wb3 + off);
        }
        f16x8 hfr[4];
        hfr[0] = *(const f16x8*)(hr0 + ks * 32);
        hfr[1] = *(const f16x8*)(hr1 + ks * 32);
        hfr[2] = *(const f16x8*)(hr2 + ks * 32);
        hfr[3] = *(const f16x8*)(hr3 + ks * 32);
        __builtin_amdgcn_s_setprio(1);
        #pragma unroll
        for (int mf = 0; mf < 4; ++mf)
            #pragma unroll
            for (int nf = 0; nf < 4; ++nf)
                acc[mf][nf] = __builtin_amdgcn_mfma_f32_16x16x32_f16(
                    hfr[mf], wbuf[cur][nf], acc[mf][nf], 0, 0, 0);
        __builtin_amdgcn_s_setprio(0);
    }
    #pragma unroll
    for (int nf = 0; nf < 4; ++nf) {
        float s = 0.f;
        #pragma unroll
        for (int mf = 0; mf < 4; ++mf)
            #pragma unroll
            for (int r = 0; r < 4; ++r)
                s += fmaxf(acc[mf][nf][r], 0.f);
        s += __shfl_xor(s, 16);
        s += __shfl_xor(s, 32);
        pacc[nf] += s;
    }
}

// ---------------------------------------------------------------------------
// Kernel 2: main fused g-network — r19 champion (102 us) + pack-then-relu
// epilogue. 256 threads = 4 waves, wave n-slice 64, double-buffered h
// (2x33 KiB padded-stride, ks-affine), 6 barriers/WG, launch_bounds(256,2)
// = 2 blocks/CU. fp16 datapath, frag-major W, ks ping-pong, setprio.
// ---------------------------------------------------------------------------
__global__ __launch_bounds__(256, 2) void rn_main(
        const _Float16* __restrict__ Abf, const _Float16* __restrict__ Bbf,
        const _Float16* __restrict__ Wt,
        const float* __restrict__ g2_b, const float* __restrict__ g3_b,
        const float* __restrict__ g4_b, float* __restrict__ partial) {
    // XCD-aware swizzle: 2048 WGs, 8 XCDs (2048 % 8 == 0 -> bijective)
    int wg = blockIdx.x;
    int swz = (wg & 7) * 256 + (wg >> 3);
    int b = swz >> 5;
    int t = swz & 31;

    __shared__ _Float16 h0[D2 * HSTRE];   // 33 KiB
    __shared__ _Float16 h1[D2 * HSTRE];   // 33 KiB

    int tid = threadIdx.x;   // 0..255
    int lane = tid & 63;
    int wid = tid >> 6;      // wave 0..3 -> n-slice of 64
    int rg = lane >> 4;      // 0..3
    int col = lane & 15;

    const _Float16* Ab  = Abf + (size_t)(b * D2) * HID;
    const _Float16* Bb0 = Bbf + (size_t)(b * D2 + t * 2 + 0) * HID;
    const _Float16* Bb1 = Bbf + (size_t)(b * D2 + t * 2 + 1) * HID;
    const _Float16* W0 = Wt;                        // 65536 elems/layer
    const _Float16* W1 = Wt + (size_t)1 * 65536;
    const _Float16* W2 = Wt + (size_t)2 * 65536;

    float pacc[4] = {0.f, 0.f, 0.f, 0.f};

    // ---- pp0 ----
    stage_h(h0, Ab, Bb0, tid);
    __syncthreads();                                         // h0 ready
    layer_sw(W0, g2_b, h0, h1, wid, rg, col, lane);          // r h0 -> w h1
    __syncthreads();                                         // h1 ready
    layer_sw(W1, g3_b, h1, h0, wid, rg, col, lane);          // r h1 -> w h0
    __syncthreads();                                         // h0 ready
    layer2_red(W2, g4_b, h0, pacc, wid, rg, col, lane);      // r h0
    stage_h(h1, Ab, Bb1, tid);                               // w h1 (overlaps)
    __syncthreads();                                         // h1 ready

    // ---- pp1 (buffers flipped) ----
    layer_sw(W0, g2_b, h1, h0, wid, rg, col, lane);
    __syncthreads();
    layer_sw(W1, g3_b, h0, h1, wid, rg, col, lane);
    __syncthreads();
    layer2_red(W2, g4_b, h1, pacc, wid, rg, col, lane);

    if (rg == 0) {
        #pragma unroll
        for (int nf = 0; nf < 4; ++nf)
            partial[(size_t)(b * NTILE + t) * HID + wid * 64 + nf * 16 + col]
                = pacc[nf];
    }
}

// ---------------------------------------------------------------------------
// Kernel 3: per-batch reduce over tiles + f-network (fp32) + log_softmax
// ---------------------------------------------------------------------------
__global__ __launch_bounds__(256) void fuse_kernel(
        const float* __restrict__ partial,
        const float* __restrict__ f1_w, const float* __restrict__ f1_b,
        const float* __restrict__ f2_w, const float* __restrict__ f2_b,
        const float* __restrict__ f3_w, const float* __restrict__ f3_b,
        float* __restrict__ out) {
    int b = blockIdx.x;
    int tid = threadIdx.x;
    __shared__ float xg[HID];
    __shared__ float h1[HID];
    __shared__ float h2v[HID];
    __shared__ float lred[NOUT];
    __shared__ float lse;

    float s = 0.f;
    for (int t = 0; t < NTILE; ++t)
        s += partial[(size_t)(b * NTILE + t) * HID + tid];
    xg[tid] = s;
    __syncthreads();

    float a1 = f1_b[tid];
    for (int k = 0; k < HID; ++k)
        a1 += xg[k] * f1_w[k * HID + tid];
    h1[tid] = a1 > 0.f ? a1 : 0.f;
    __syncthreads();

    float a2 = f2_b[tid];
    for (int k = 0; k < HID; ++k)
        a2 += h1[k] * f2_w[k * HID + tid];
    h2v[tid] = a2 > 0.f ? a2 : 0.f;
    __syncthreads();

    float logit = 0.f;
    if (tid < NOUT) {
        logit = f3_b[tid];
        for (int k = 0; k < HID; ++k)
            logit += h2v[k] * f3_w[k * NOUT + tid];
        lred[tid] = logit;
    }
    __syncthreads();
    if (tid == 0) {
        float mx = lred[0];
        for (int j = 1; j < NOUT; ++j) mx = fmaxf(mx, lred[j]);
        float se = 0.f;
        for (int j = 0; j < NOUT; ++j) se += expf(lred[j] - mx);
        lse = mx + logf(se);
    }
    __syncthreads();
    if (tid < NOUT)
        out[b * NOUT + tid] = logit - lse;
}

// ---------------------------------------------------------------------------
extern "C" void kernel_launch(void* const* d_in, const int* in_sizes, int n_in,
                              void* d_out, int out_size, void* d_ws, size_t ws_size,
                              hipStream_t stream) {
    const float* x    = (const float*)d_in[0];
    const float* qst  = (const float*)d_in[1];
    const float* g1_w = (const float*)d_in[2];
    const float* g1_b = (const float*)d_in[3];
    const float* g2_w = (const float*)d_in[4];
    const float* g2_b = (const float*)d_in[5];
    const float* g3_w = (const float*)d_in[6];
    const float* g3_b = (const float*)d_in[7];
    const float* g4_w = (const float*)d_in[8];
    const float* g4_b = (const float*)d_in[9];
    const float* f1_w = (const float*)d_in[10];
    const float* f1_b = (const float*)d_in[11];
    const float* f2_w = (const float*)d_in[12];
    const float* f2_b = (const float*)d_in[13];
    const float* f3_w = (const float*)d_in[14];
    const float* f3_b = (const float*)d_in[15];
    float* out = (float*)d_out;

    char* ws = (char*)d_ws;
    _Float16* Abf = (_Float16*)ws;                          // 2 MiB
    _Float16* Bbf = (_Float16*)(ws + (2u << 20));           // 2 MiB
    _Float16* Wt  = (_Float16*)(ws + (4u << 20));           // 384 KiB
    float* partial = (float*)(ws + (4u << 20) + (512u << 10));   // 2 MiB

    prep_all<<<384 + 4 * NB, 256, 0, stream>>>(x, qst, g1_w, g1_b, g2_w, g3_w, g4_w,
                                               Abf, Bbf, Wt);
    rn_main<<<NB * NTILE, 256, 0, stream>>>(Abf, Bbf, Wt, g2_b, g3_b, g4_b, partial);
    fuse_kernel<<<NB, 256, 0, stream>>>(partial, f1_w, f1_b, f2_w, f2_b, f3_w, f3_b, out);
}

// Round 21
// 114.912 us; speedup vs baseline: 4.5446x; 1.0318x over previous
//
#include <hip/hip_runtime.h>
#include <hip/hip_bf16.h>
#include <math.h>

#define NB   64      // batch
#define D2   64      // objects per batch
#define OBJ  26      // K+2 features per object
#define NQST 11
#define HID  256
#define NOUT 28
#define NTILE 32     // p-tiles per batch (2 p's each, processed sequentially)
#define HSTRE 264    // h row stride in fp16 ELEMENTS (528 B): 2-way-free banks
                     // AND ks-affine addresses (ds offset immediates)

typedef _Float16 f16x8 __attribute__((ext_vector_type(8)));
typedef _Float16 f16x4 __attribute__((ext_vector_type(4)));
typedef __attribute__((ext_vector_type(4))) float f32x4;
typedef __attribute__((ext_vector_type(2))) unsigned int u32x2;

__device__ __forceinline__ unsigned pack_h2(float a, float b) {
    auto r = __builtin_amdgcn_cvt_pkrtz(a, b);   // v_cvt_pkrtz_f16_f32
    union U { decltype(r) h; unsigned u; } v;
    v.h = r;
    return v.u;
}
__device__ __forceinline__ f16x8 relu8(f16x8 x) {
    f16x8 z = {0, 0, 0, 0, 0, 0, 0, 0};
#if __has_builtin(__builtin_elementwise_max)
    return __builtin_elementwise_max(x, z);    // v_pk_max_f16 x4
#else
    #pragma unroll
    for (int j = 0; j < 8; ++j) x[j] = x[j] > (_Float16)0 ? x[j] : (_Float16)0;
    return x;
#endif
}
// pack 4 f32 -> 4 fp16 (rtz) then relu in packed fp16: 2 cvt_pk + 2 pk_max
__device__ __forceinline__ u32x2 pack_relu4(float a0, float a1, float a2, float a3) {
    u32x2 w;
    w[0] = pack_h2(a0, a1);
    w[1] = pack_h2(a2, a3);
#if __has_builtin(__builtin_elementwise_max)
    union { u32x2 u; f16x4 h; } v;
    v.u = w;
    f16x4 z = {0, 0, 0, 0};
    v.h = __builtin_elementwise_max(v.h, z);
    return v.u;
#else
    union { u32x2 u; f16x4 h; } v; v.u = w;
    #pragma unroll
    for (int j = 0; j < 4; ++j) v.h[j] = v.h[j] > (_Float16)0 ? v.h[j] : (_Float16)0;
    return v.u;
#endif
}

// ---------------------------------------------------------------------------
// Kernel 1 (merged):
// blocks 0..383: FRAG-MAJOR weight repack (fp16). Block = ((l*16+nb)*8+ks);
//   element e = lane*8+j holds W_l[k][n], n = nb*16+(lane&15),
//   k = ks*32+(lane>>4)*8+j. Main-kernel W-frag load = ONE contiguous 1 KB
//   burst at base + ks*1024B.
// blocks 384..639: per-batch A/B (fp16), 4 blocks per batch (16 q-rows each):
//   A[q] = o[q] @ g1_w[0:26]
//   B[p] = o[p] @ g1_w[26:52] + qst @ g1_w[52:63] + g1_b
// ---------------------------------------------------------------------------
__global__ __launch_bounds__(256) void prep_all(
        const float* __restrict__ x, const float* __restrict__ qst,
        const float* __restrict__ g1_w, const float* __restrict__ g1_b,
        const float* __restrict__ g2_w, const float* __restrict__ g3_w,
        const float* __restrict__ g4_w,
        _Float16* __restrict__ Abf, _Float16* __restrict__ Bbf,
        _Float16* __restrict__ Wt) {
    if (blockIdx.x < 384) {
        int blk = blockIdx.x;
        int ks = blk & 7;
        int nbl = blk >> 3;      // l*16+nb
        int l = nbl >> 4;
        int nb = nbl & 15;
        const float* W = (l == 0) ? g2_w : ((l == 1) ? g3_w : g4_w);
        int t = threadIdx.x;
        #pragma unroll
        for (int u = 0; u < 2; ++u) {
            int e = t + u * 256;             // 0..511
            int lane = e >> 3;
            int j = e & 7;
            int n = nb * 16 + (lane & 15);
            int k = ks * 32 + (lane >> 4) * 8 + j;
            Wt[blk * 512 + e] = (_Float16)W[k * HID + n];
        }
        return;
    }
    int blk = blockIdx.x - 384;
    int b = blk >> 2;            // batch
    int q0 = (blk & 3) * 16;     // 16 q-rows per block
    int tid = threadIdx.x;
    __shared__ float o_lds[16][OBJ];
    for (int idx = tid; idx < 24 * 16; idx += 256) {
        int c = idx >> 4, i = idx & 15;
        o_lds[i][c] = x[(b * 24 + c) * D2 + q0 + i];
    }
    if (tid < 16) {
        int q = q0 + tid;
        o_lds[tid][24] = (float)(q & 7) * (8.0f / 7.0f) - 4.0f;  // cx
        o_lds[tid][25] = (float)(q >> 3) * (8.0f / 7.0f) - 4.0f; // cy
    }
    __syncthreads();
    int n = tid;  // 0..255
    float qpart = g1_b[n];
    for (int s = 0; s < NQST; ++s)
        qpart += qst[b * NQST + s] * g1_w[(2 * OBJ + s) * HID + n];
    float accA[16], accB[16];
    #pragma unroll
    for (int i = 0; i < 16; ++i) { accA[i] = 0.f; accB[i] = 0.f; }
    for (int c = 0; c < OBJ; ++c) {
        float wA = g1_w[c * HID + n];
        float wB = g1_w[(OBJ + c) * HID + n];
        #pragma unroll
        for (int i = 0; i < 16; ++i) {
            float ov = o_lds[i][c];
            accA[i] += ov * wA;
            accB[i] += ov * wB;
        }
    }
    #pragma unroll
    for (int i = 0; i < 16; ++i) {
        int q = q0 + i;
        Abf[(b * D2 + q) * HID + n] = (_Float16)accA[i];
        Bbf[(b * D2 + q) * HID + n] = (_Float16)(accB[i] + qpart);
    }
}

// ---------------------------------------------------------------------------
// rn_main helpers. 256 threads = 4 waves, per-wave n-slice 64.
// h LDS layout: row m at element m*HSTRE, k element K at index K in row.
// ---------------------------------------------------------------------------

// stage h[m][k] = relu(A[m][k] + B[k]) into hbuf.
__device__ __forceinline__ void stage_h(
        _Float16* hbuf, const _Float16* __restrict__ Ab,
        const _Float16* __restrict__ Bb, int tid) {
    #pragma unroll 2
    for (int i = 0; i < 8; ++i) {
        int c = tid + i * 256;       // 2048 chunks of 8 fp16
        int m = c >> 5;              // 0..63
        int k0 = (c & 31) * 8;
        f16x8 av = *(const f16x8*)(Ab + m * HID + k0);
        f16x8 bv = *(const f16x8*)(Bb + k0);
        f16x8 hv = relu8(av + bv);   // 4x pk_add + 4x pk_max
        *(f16x8*)(hbuf + m * HSTRE + k0) = hv;
    }
}

// layers 0/1: swapped-operand mfma(W,h) -> D[n][m]; bias-in-acc; epilogue
// pack-then-relu (2 cvt_pk + 2 pk_max per frag) -> OTHER buffer.
// W: frag-major bursts, ks ping-pong (wbuf[2][4]). setprio around MFMAs.
__device__ __forceinline__ void layer_sw(
        const _Float16* __restrict__ Wl, const float* __restrict__ bias,
        const _Float16* hin, _Float16* hout,
        int wid, int rg, int col, int lane) {
    const _Float16* wb0 = Wl + (size_t)(wid * 4 + 0) * 4096 + lane * 8;
    const _Float16* wb1 = Wl + (size_t)(wid * 4 + 1) * 4096 + lane * 8;
    const _Float16* wb2 = Wl + (size_t)(wid * 4 + 2) * 4096 + lane * 8;
    const _Float16* wb3 = Wl + (size_t)(wid * 4 + 3) * 4096 + lane * 8;

    f32x4 acc[4][4];   // [nf][mf]
    #pragma unroll
    for (int nf = 0; nf < 4; ++nf) {
        f32x4 b4 = *(const f32x4*)(bias + wid * 64 + nf * 16 + rg * 4);
        #pragma unroll
        for (int mf = 0; mf < 4; ++mf)
            acc[nf][mf] = b4;               // bias-in-acc
    }

    const _Float16* hr0 = hin + (0 * 16 + col) * HSTRE + rg * 8;
    const _Float16* hr1 = hin + (1 * 16 + col) * HSTRE + rg * 8;
    const _Float16* hr2 = hin + (2 * 16 + col) * HSTRE + rg * 8;
    const _Float16* hr3 = hin + (3 * 16 + col) * HSTRE + rg * 8;

    f16x8 wbuf[2][4];   // ks ping-pong: 32 regs in flight
    wbuf[0][0] = *(const f16x8*)(wb0);
    wbuf[0][1] = *(const f16x8*)(wb1);
    wbuf[0][2] = *(const f16x8*)(wb2);
    wbuf[0][3] = *(const f16x8*)(wb3);

    #pragma unroll
    for (int ks = 0; ks < 8; ++ks) {
        const int cur = ks & 1;
        if (ks < 7) {
            int off = (ks + 1) * 512;
            wbuf[cur ^ 1][0] = *(const f16x8*)(wb0 + off);
            wbuf[cur ^ 1][1] = *(const f16x8*)(wb1 + off);
            wbuf[cur ^ 1][2] = *(const f16x8*)(wb2 + off);
            wbuf[cur ^ 1][3] = *(const f16x8*)(wb3 + off);
        }
        f16x8 hfr[4];
        hfr[0] = *(const f16x8*)(hr0 + ks * 32);
        hfr[1] = *(const f16x8*)(hr1 + ks * 32);
        hfr[2] = *(const f16x8*)(hr2 + ks * 32);
        hfr[3] = *(const f16x8*)(hr3 + ks * 32);
        __builtin_amdgcn_s_setprio(1);
        #pragma unroll
        for (int nf = 0; nf < 4; ++nf)
            #pragma unroll
            for (int mf = 0; mf < 4; ++mf)
                acc[nf][mf] = __builtin_amdgcn_mfma_f32_16x16x32_f16(
                    wbuf[cur][nf], hfr[mf], acc[nf][mf], 0, 0, 0);
        __builtin_amdgcn_s_setprio(0);
    }
    // epilogue: n = wid*64+nf*16+rg*4+r, m = mf*16+col -> hout
    #pragma unroll
    for (int nf = 0; nf < 4; ++nf) {
        int n0 = wid * 64 + nf * 16 + rg * 4;
        #pragma unroll
        for (int mf = 0; mf < 4; ++mf) {
            int m = mf * 16 + col;
            u32x2 w = pack_relu4(acc[nf][mf][0], acc[nf][mf][1],
                                 acc[nf][mf][2], acc[nf][mf][3]);
            *(u32x2*)(hout + m * HSTRE + n0) = w;
        }
    }
}

// layer 2: unswapped mfma(h,W) -> D[m][n]; bias-in-acc; relu + pair-sum.
// Same frag-major ks ping-pong + setprio.
__device__ __forceinline__ void layer2_red(
        const _Float16* __restrict__ Wl, const float* __restrict__ bias,
        const _Float16* hin, float* pacc, int wid, int rg, int col, int lane) {
    const _Float16* wb0 = Wl + (size_t)(wid * 4 + 0) * 4096 + lane * 8;
    const _Float16* wb1 = Wl + (size_t)(wid * 4 + 1) * 4096 + lane * 8;
    const _Float16* wb2 = Wl + (size_t)(wid * 4 + 2) * 4096 + lane * 8;
    const _Float16* wb3 = Wl + (size_t)(wid * 4 + 3) * 4096 + lane * 8;

    f32x4 acc[4][4];   // [mf][nf]
    #pragma unroll
    for (int nf = 0; nf < 4; ++nf) {
        float bv = bias[wid * 64 + nf * 16 + col];
        f32x4 bb = (f32x4){bv, bv, bv, bv};
        #pragma unroll
        for (int mf = 0; mf < 4; ++mf)
            acc[mf][nf] = bb;
    }

    const _Float16* hr0 = hin + (0 * 16 + col) * HSTRE + rg * 8;
    const _Float16* hr1 = hin + (1 * 16 + col) * HSTRE + rg * 8;
    const _Float16* hr2 = hin + (2 * 16 + col) * HSTRE + rg * 8;
    const _Float16* hr3 = hin + (3 * 16 + col) * HSTRE + rg * 8;

    f16x8 wbuf[2][4];
    wbuf[0][0] = *(const f16x8*)(wb0);
    wbuf[0][1] = *(const f16x8*)(wb1);
    wbuf[0][2] = *(const f16x8*)(wb2);
    wbuf[0][3] = *(const f16x8*)(wb3);

    #pragma unroll
    for (int ks = 0; ks < 8; ++ks) {
        const int cur = ks & 1;
        if (ks < 7) {
            int off = (ks + 1) * 512;
            wbuf[cur ^ 1][0] = *(const f16x8*)(wb0 + off);
            wbuf[cur ^ 1][1] = *(const f16x8*)(wb1 + off);
            wbuf[cur ^ 1][2] = *(const f16x8*)(wb2 + off);
            wbuf[cur ^ 1][3] = *(const f16x8*)(wb3 + off);
        }
        f16x8 hfr[4];
        hfr[0] = *(const f16x8*)(hr0 + ks * 32);
        hfr[1] = *(const f16x8*)(hr1 + ks * 32);
        hfr[2] = *(const f16x8*)(hr2 + ks * 32);
        hfr[3] = *(const f16x8*)(hr3 + ks * 32);
        __builtin_amdgcn_s_setprio(1);
        #pragma unroll
        for (int mf = 0; mf < 4; ++mf)
            #pragma unroll
            for (int nf = 0; nf < 4; ++nf)
                acc[mf][nf] = __builtin_amdgcn_mfma_f32_16x16x32_f16(
                    hfr[mf], wbuf[cur][nf], acc[mf][nf], 0, 0, 0);
        __builtin_amdgcn_s_setprio(0);
    }
    #pragma unroll
    for (int nf = 0; nf < 4; ++nf) {
        float s = 0.f;
        #pragma unroll
        for (int mf = 0; mf < 4; ++mf)
            #pragma unroll
            for (int r = 0; r < 4; ++r)
                s += fmaxf(acc[mf][nf][r], 0.f);
        s += __shfl_xor(s, 16);
        s += __shfl_xor(s, 32);
        pacc[nf] += s;
    }
}

// ---------------------------------------------------------------------------
// Kernel 2: main fused g-network — r20 champion, FROZEN.
// ---------------------------------------------------------------------------
__global__ __launch_bounds__(256, 2) void rn_main(
        const _Float16* __restrict__ Abf, const _Float16* __restrict__ Bbf,
        const _Float16* __restrict__ Wt,
        const float* __restrict__ g2_b, const float* __restrict__ g3_b,
        const float* __restrict__ g4_b, float* __restrict__ partial) {
    // XCD-aware swizzle: 2048 WGs, 8 XCDs (2048 % 8 == 0 -> bijective)
    int wg = blockIdx.x;
    int swz = (wg & 7) * 256 + (wg >> 3);
    int b = swz >> 5;
    int t = swz & 31;

    __shared__ _Float16 h0[D2 * HSTRE];   // 33 KiB
    __shared__ _Float16 h1[D2 * HSTRE];   // 33 KiB

    int tid = threadIdx.x;   // 0..255
    int lane = tid & 63;
    int wid = tid >> 6;      // wave 0..3 -> n-slice of 64
    int rg = lane >> 4;      // 0..3
    int col = lane & 15;

    const _Float16* Ab  = Abf + (size_t)(b * D2) * HID;
    const _Float16* Bb0 = Bbf + (size_t)(b * D2 + t * 2 + 0) * HID;
    const _Float16* Bb1 = Bbf + (size_t)(b * D2 + t * 2 + 1) * HID;
    const _Float16* W0 = Wt;                        // 65536 elems/layer
    const _Float16* W1 = Wt + (size_t)1 * 65536;
    const _Float16* W2 = Wt + (size_t)2 * 65536;

    float pacc[4] = {0.f, 0.f, 0.f, 0.f};

    // ---- pp0 ----
    stage_h(h0, Ab, Bb0, tid);
    __syncthreads();                                         // h0 ready
    layer_sw(W0, g2_b, h0, h1, wid, rg, col, lane);          // r h0 -> w h1
    __syncthreads();                                         // h1 ready
    layer_sw(W1, g3_b, h1, h0, wid, rg, col, lane);          // r h1 -> w h0
    __syncthreads();                                         // h0 ready
    layer2_red(W2, g4_b, h0, pacc, wid, rg, col, lane);      // r h0
    stage_h(h1, Ab, Bb1, tid);                               // w h1 (overlaps)
    __syncthreads();                                         // h1 ready

    // ---- pp1 (buffers flipped) ----
    layer_sw(W0, g2_b, h1, h0, wid, rg, col, lane);
    __syncthreads();
    layer_sw(W1, g3_b, h0, h1, wid, rg, col, lane);
    __syncthreads();
    layer2_red(W2, g4_b, h1, pacc, wid, rg, col, lane);

    if (rg == 0) {
        #pragma unroll
        for (int nf = 0; nf < 4; ++nf)
            partial[(size_t)(b * NTILE + t) * HID + wid * 64 + nf * 16 + col]
                = pacc[nf];
    }
}

// ---------------------------------------------------------------------------
// Kernel 3: per-batch reduce over tiles + f-network (fp32) + log_softmax.
// PARALLELIZED: 1024 threads = (n:256, kg:4); each layer's 256-deep serial
// FMA chain split into 4 independent 64-deep chains + LDS partial reduce
// (the old 256-thread version was a 256-FMA latency chain, 64 blocks on
// 256 CUs -> pure latency, ~no ILP since fp32 can't reassociate).
// ---------------------------------------------------------------------------
__global__ __launch_bounds__(1024) void fuse_kernel(
        const float* __restrict__ partial,
        const float* __restrict__ f1_w, const float* __restrict__ f1_b,
        const float* __restrict__ f2_w, const float* __restrict__ f2_b,
        const float* __restrict__ f3_w, const float* __restrict__ f3_b,
        float* __restrict__ out) {
    int b = blockIdx.x;
    int tid = threadIdx.x;        // 0..1023
    int n = tid & 255;            // feature
    int kg = tid >> 8;            // 0..3 k-group
    __shared__ float xg[HID];
    __shared__ float pbuf[4][HID];
    __shared__ float h1[HID];
    __shared__ float h2v[HID];
    __shared__ float lred[NOUT];
    __shared__ float lse;

    // xg: each kg sums 8 tiles
    {
        float s = 0.f;
        #pragma unroll
        for (int u = 0; u < 8; ++u)
            s += partial[(size_t)(b * NTILE + kg * 8 + u) * HID + n];
        pbuf[kg][n] = s;
    }
    __syncthreads();
    if (tid < HID)
        xg[n] = pbuf[0][n] + pbuf[1][n] + pbuf[2][n] + pbuf[3][n];
    __syncthreads();

    // f1: 64 k's per kg
    {
        float a = 0.f;
        #pragma unroll 4
        for (int k = kg * 64; k < kg * 64 + 64; ++k)
            a += xg[k] * f1_w[k * HID + n];
        pbuf[kg][n] = a;
    }
    __syncthreads();
    if (tid < HID) {
        float a1 = f1_b[n] + pbuf[0][n] + pbuf[1][n] + pbuf[2][n] + pbuf[3][n];
        h1[n] = a1 > 0.f ? a1 : 0.f;
    }
    __syncthreads();

    // f2
    {
        float a = 0.f;
        #pragma unroll 4
        for (int k = kg * 64; k < kg * 64 + 64; ++k)
            a += h1[k] * f2_w[k * HID + n];
        pbuf[kg][n] = a;
    }
    __syncthreads();
    if (tid < HID) {
        float a2 = f2_b[n] + pbuf[0][n] + pbuf[1][n] + pbuf[2][n] + pbuf[3][n];
        h2v[n] = a2 > 0.f ? a2 : 0.f;
    }
    __syncthreads();

    // f3: 28 outputs, 64 k's per kg
    if (n < NOUT) {
        float a = 0.f;
        #pragma unroll 4
        for (int k = kg * 64; k < kg * 64 + 64; ++k)
            a += h2v[k] * f3_w[k * NOUT + n];
        pbuf[kg][n] = a;
    }
    __syncthreads();
    if (tid < NOUT)
        lred[tid] = f3_b[tid] + pbuf[0][tid] + pbuf[1][tid]
                  + pbuf[2][tid] + pbuf[3][tid];
    __syncthreads();
    if (tid == 0) {
        float mx = lred[0];
        for (int j = 1; j < NOUT; ++j) mx = fmaxf(mx, lred[j]);
        float se = 0.f;
        for (int j = 0; j < NOUT; ++j) se += expf(lred[j] - mx);
        lse = mx + logf(se);
    }
    __syncthreads();
    if (tid < NOUT)
        out[b * NOUT + tid] = lred[tid] - lse;
}

// ---------------------------------------------------------------------------
extern "C" void kernel_launch(void* const* d_in, const int* in_sizes, int n_in,
                              void* d_out, int out_size, void* d_ws, size_t ws_size,
                              hipStream_t stream) {
    const float* x    = (const float*)d_in[0];
    const float* qst  = (const float*)d_in[1];
    const float* g1_w = (const float*)d_in[2];
    const float* g1_b = (const float*)d_in[3];
    const float* g2_w = (const float*)d_in[4];
    const float* g2_b = (const float*)d_in[5];
    const float* g3_w = (const float*)d_in[6];
    const float* g3_b = (const float*)d_in[7];
    const float* g4_w = (const float*)d_in[8];
    const float* g4_b = (const float*)d_in[9];
    const float* f1_w = (const float*)d_in[10];
    const float* f1_b = (const float*)d_in[11];
    const float* f2_w = (const float*)d_in[12];
    const float* f2_b = (const float*)d_in[13];
    const float* f3_w = (const float*)d_in[14];
    const float* f3_b = (const float*)d_in[15];
    float* out = (float*)d_out;

    char* ws = (char*)d_ws;
    _Float16* Abf = (_Float16*)ws;                          // 2 MiB
    _Float16* Bbf = (_Float16*)(ws + (2u << 20));           // 2 MiB
    _Float16* Wt  = (_Float16*)(ws + (4u << 20));           // 384 KiB
    float* partial = (float*)(ws + (4u << 20) + (512u << 10));   // 2 MiB

    prep_all<<<384 + 4 * NB, 256, 0, stream>>>(x, qst, g1_w, g1_b, g2_w, g3_w, g4_w,
                                               Abf, Bbf, Wt);
    rn_main<<<NB * NTILE, 256, 0, stream>>>(Abf, Bbf, Wt, g2_b, g3_b, g4_b, partial);
    fuse_kernel<<<NB, 1024, 0, stream>>>(partial, f1_w, f1_b, f2_w, f2_b, f3_w, f3_b, out);
}